// Round 7
// baseline (4169.468 us; speedup 1.0000x reference)
//
#include <hip/hip_runtime.h>
#include <hip/hip_fp16.h>
#include <math.h>

#define BB 128
#define TT 512
#define DD 256
#define HH 256
#define NG 1024  // 4*H

typedef _Float16 h2_t __attribute__((ext_vector_type(2)));
typedef _Float16 f16x8 __attribute__((ext_vector_type(8)));
typedef float f32x4 __attribute__((ext_vector_type(4)));

#if __has_builtin(__builtin_amdgcn_fdot2)
__device__ __forceinline__ float fdot2_(h2_t a, h2_t b, float c) {
    return __builtin_amdgcn_fdot2(a, b, c, false);
}
#else
__device__ __forceinline__ float fdot2_(h2_t a, h2_t b, float c) {
    return c + (float)a.x * (float)b.x + (float)a.y * (float)b.y;
}
#endif

__device__ __forceinline__ float sigmoidf_(float x) {
    return 1.0f / (1.0f + __expf(-x));
}
__device__ __forceinline__ float tanhf_(float x) {
    x = fminf(15.0f, fmaxf(-15.0f, x));
    float e = __expf(2.0f * x);
    return (e - 1.0f) / (e + 1.0f);
}
__device__ __forceinline__ void dot4_(float4& acc, uint4 u, h2_t h) {
    acc.x = fdot2_(__builtin_bit_cast(h2_t, u.x), h, acc.x);
    acc.y = fdot2_(__builtin_bit_cast(h2_t, u.y), h, acc.y);
    acc.z = fdot2_(__builtin_bit_cast(h2_t, u.z), h, acc.z);
    acc.w = fdot2_(__builtin_bit_cast(h2_t, u.w), h, acc.w);
}

// AGPR-resident value read as one full-rate VALU op. NON-volatile (R3's
// volatile chain serialized the loop) but with a dummy loop-variant operand
// (dep = tt) so LICM cannot hoist the 192 reads out of the timestep loop
// (the values are loop-invariant; nominal tt-dependence blocks hoisting
// while leaving the scheduler free to interleave with dot2s).
__device__ __forceinline__ uint ar_(const uint& a, int dep) {
    uint v;
    asm("v_accvgpr_read_b32 %0, %1" : "=v"(v) : "a"(a), "v"(dep));
    return v;
}

// Pair sum across lanes (l, l^1) via DPP quad_perm [1,0,3,2] — VALU pipe.
#if __has_builtin(__builtin_amdgcn_update_dpp)
__device__ __forceinline__ float pair_sum_(float v) {
    int x = __builtin_bit_cast(int, v);
    int y = __builtin_amdgcn_update_dpp(0, x, 0xB1, 0xF, 0xF, true);
    return v + __builtin_bit_cast(float, y);
}
#else
__device__ __forceinline__ float pair_sum_(float v) {
    return v + __shfl_xor(v, 1, 64);
}
#endif

// Pack: packed col n = j*4+q <-> gate row g = q*256+j  (q: 0=i,1=f,2=g,3=o)
//  Wg16 [n][k] fp16            (MFMA GEMM B operand)
//  Wi16/Wh16 fp16 k-pair-major (halfs at ((k>>1)*1024 + n)*2 + (k&1))
//  bias_p[n] = b_ih[g] + b_hh[g]
__global__ void pack2(const float* __restrict__ W_ih, const float* __restrict__ W_hh,
                      const float* __restrict__ b_ih, const float* __restrict__ b_hh,
                      __half* __restrict__ Wg16, __half* __restrict__ Wi16,
                      __half* __restrict__ Wh16, float* __restrict__ bias_p) {
    int idx = blockIdx.x * 256 + threadIdx.x;   // 0..262143
    int n = idx >> 8;
    int k = idx & 255;
    int g = (n & 3) * 256 + (n >> 2);
    float wih = W_ih[g * 256 + k];
    float whh = W_hh[g * 256 + k];
    Wg16[n * 256 + k] = __float2half(wih);
    size_t hidx = ((size_t)(k >> 1) * 1024 + n) * 2 + (k & 1);
    Wi16[hidx] = __float2half(wih);
    Wh16[hidx] = __float2half(whh);
    if (idx < 1024) {
        int gg = (idx & 3) * 256 + (idx >> 2);
        bias_p[idx] = b_ih[gg] + b_hh[gg];
    }
}

// x fp32 -> fp16, 8 elements/thread
__global__ __launch_bounds__(256) void cvt_x(const float* __restrict__ X,
                                             __half* __restrict__ X16) {
    size_t i = ((size_t)blockIdx.x * 256 + threadIdx.x) * 8;
    float4 a = *(const float4*)&X[i];
    float4 b = *(const float4*)&X[i + 4];
    f16x8 v;
    v[0] = (_Float16)a.x; v[1] = (_Float16)a.y; v[2] = (_Float16)a.z; v[3] = (_Float16)a.w;
    v[4] = (_Float16)b.x; v[5] = (_Float16)b.y; v[6] = (_Float16)b.z; v[7] = (_Float16)b.w;
    *(f16x8*)&X16[i] = v;
}

// xg chunk GEMM via MFMA f16: M = 128*Tc, N = 1024, K = 256.
__global__ __launch_bounds__(256) void xg_gemm_mfma(const __half* __restrict__ X16,
                                                    const __half* __restrict__ Wg16,
                                                    const float* __restrict__ bias_p,
                                                    __half* __restrict__ xg,
                                                    int t0, int lTc, int tcMask) {
    __shared__ __align__(16) __half st[4][16][72];
    int tid = threadIdx.x;
    int w = tid >> 6, lane = tid & 63;
    int row16 = lane & 15, quad = lane >> 4;
    int m0 = blockIdx.x * 64 + w * 16;
    int n0 = blockIdx.y * 64;

    int mrow = m0 + row16;                                   // chunk-local row
    size_t xrow = (size_t)(mrow >> lTc) * 512 + t0 + (mrow & tcMask);
    const __half* aptr = X16 + xrow * 256 + quad * 8;
    f16x8 afrag[8];
#pragma unroll
    for (int kk = 0; kk < 8; ++kk)
        afrag[kk] = *(const f16x8*)(aptr + kk * 32);

#pragma unroll
    for (int cg = 0; cg < 4; ++cg) {
        int n = n0 + cg * 16 + row16;
        const __half* bptr = Wg16 + (size_t)n * 256 + quad * 8;
        f32x4 acc = {0.0f, 0.0f, 0.0f, 0.0f};
#pragma unroll
        for (int kk = 0; kk < 8; ++kk) {
            f16x8 bfrag = *(const f16x8*)(bptr + kk * 32);
            acc = __builtin_amdgcn_mfma_f32_16x16x32_f16(afrag[kk], bfrag, acc, 0, 0, 0);
        }
        float bias = bias_p[n];
#pragma unroll
        for (int r = 0; r < 4; ++r)
            st[w][quad * 4 + r][cg * 16 + row16] = __float2half(acc[r] + bias);
    }
    __syncthreads();
    int ml = lane >> 2, cq = lane & 3;
    int mout = blockIdx.x * 64 + w * 16 + ml;                // chunk-local row
    const uint4* src = (const uint4*)&st[w][ml][cq * 16];
    uint4 v0 = src[0], v1 = src[1];
    *(uint4*)&xg[(size_t)mout * 1024 + n0 + cq * 16] = v0;
    *(uint4*)&xg[(size_t)mout * 1024 + n0 + cq * 16 + 8] = v1;
}

// Recurrence v8: R6 structure with ALL weights register-resident.
// R6 diagnosis: step was L1-return-bound — the allocator kept only part of
// wreg[44] and remat'd ~196 KB/block/step of weight reloads through L1
// (~3100 cyc of the 4130-cyc step). v8 residency per thread (kh-half,
// 64 k-pairs):
//   k-pairs  0..15 : wreg[16] arch VGPR (64 regs; live arch ~100, below the
//                    measured ~120 remat threshold -> stays resident)
//   k-pairs 16..63 : wa4[48] = 192 AGPRs (R3/R4 proved alloc works), read
//                    in-loop via NON-volatile tt-dependent v_accvgpr_read
//                    (schedulable, un-hoistable; R3's volatile chain was
//                    the regression, not the reads)
// No lw LDS array, no streamed weights, no per-step weight VMEM at all.
// Per-step VMEM = 8 B/thread xg. LDS = hs broadcasts only.
__global__ __launch_bounds__(512, 2) void lstm_rec4(const __half* __restrict__ xg,
                                                    const __half* __restrict__ Wh16,
                                                    const int* __restrict__ x_len,
                                                    float* __restrict__ out,
                                                    __half* __restrict__ h_state,
                                                    float* __restrict__ c_state,
                                                    int t0, int Tc) {
    __shared__ __align__(16) __half hs[2][272];     // padded double-buffered h
    int tid = threadIdx.x;
    int c = tid >> 1, kh = tid & 1;
    int b = blockIdx.x;
    int len = x_len[b];
    const uint4* W4 = (const uint4*)Wh16;           // index: p*256 + c  (p = k-pair)

    const uint4* wp = W4 + (size_t)(kh * 64) * 256 + c;
    // k-pairs 0..15 in arch VGPRs (allocator-managed, below remat threshold)
    uint4 wreg[16];
#pragma unroll
    for (int i = 0; i < 16; ++i) wreg[i] = wp[(size_t)i * 256];
    // k-pairs 16..63 in AGPRs (pinned; asm results cannot be rematerialized)
    uint4 wa4[48];
#pragma unroll
    for (int i = 0; i < 48; ++i) wa4[i] = wp[(size_t)(16 + i) * 256];
#pragma unroll
    for (int i = 0; i < 48; ++i)
        asm volatile("" : "+a"(wa4[i].x), "+a"(wa4[i].y),
                          "+a"(wa4[i].z), "+a"(wa4[i].w));

    float cst = 0.0f;
    float hlast = 0.0f;
    if (t0 != 0) cst = c_state[b * 256 + c];        // replicated in both lanes
    if (kh == 0)
        hs[0][c + ((c >> 7) << 4)] = (t0 == 0) ? __float2half(0.0f)
                                               : h_state[b * 256 + c];

    const __half* xgb = xg + (size_t)b * Tc * 1024 + 4 * c;
    float* outb = out + ((size_t)b * 512 + t0) * 256 + c;
    __syncthreads();

    for (int tt = 0; tt < Tc; ++tt) {
        uint2 xr = *(const uint2*)(xgb + (size_t)tt * 1024);

        // kh-half base: kh=0 -> uint4 idx 0, kh=1 -> idx 18 (byte 288)
        const uint4* h4 = (const uint4*)(hs[tt & 1]) + kh * 18;
        float4 acc = {0.0f, 0.0f, 0.0f, 0.0f};
        // j = 0..3: k-pairs 0..15 in arch VGPRs
#pragma unroll
        for (int j = 0; j < 4; ++j) {
            uint4 hv = h4[j];
            dot4_(acc, wreg[j * 4 + 0], __builtin_bit_cast(h2_t, hv.x));
            dot4_(acc, wreg[j * 4 + 1], __builtin_bit_cast(h2_t, hv.y));
            dot4_(acc, wreg[j * 4 + 2], __builtin_bit_cast(h2_t, hv.z));
            dot4_(acc, wreg[j * 4 + 3], __builtin_bit_cast(h2_t, hv.w));
        }
        // j = 4..15: k-pairs 16..63 in AGPRs
#define DOT4A(ai, hx)                                                          \
        {                                                                      \
            h2_t hh = __builtin_bit_cast(h2_t, hx);                            \
            acc.x = fdot2_(__builtin_bit_cast(h2_t, ar_(wa4[ai].x, tt)), hh, acc.x); \
            acc.y = fdot2_(__builtin_bit_cast(h2_t, ar_(wa4[ai].y, tt)), hh, acc.y); \
            acc.z = fdot2_(__builtin_bit_cast(h2_t, ar_(wa4[ai].z, tt)), hh, acc.z); \
            acc.w = fdot2_(__builtin_bit_cast(h2_t, ar_(wa4[ai].w, tt)), hh, acc.w); \
        }
#pragma unroll
        for (int j = 4; j < 16; ++j) {
            uint4 hv = h4[j];
            int a0 = (j - 4) * 4;
            DOT4A(a0 + 0, hv.x);
            DOT4A(a0 + 1, hv.y);
            DOT4A(a0 + 2, hv.z);
            DOT4A(a0 + 3, hv.w);
        }
#undef DOT4A
        // reduce partials over kh (lanes l, l^1) on the VALU pipe
        float gi = pair_sum_(acc.x);
        float gf = pair_sum_(acc.y);
        float gg = pair_sum_(acc.z);
        float go = pair_sum_(acc.w);
        h2_t x01 = __builtin_bit_cast(h2_t, xr.x);
        h2_t x23 = __builtin_bit_cast(h2_t, xr.y);
        gi += (float)x01.x;
        gf += (float)x01.y;
        gg += (float)x23.x;
        go += (float)x23.y;
        // gate math: both lanes redundantly (identical inputs -> identical cst)
        float iv = sigmoidf_(gi), fv = sigmoidf_(gf);
        float gv = tanhf_(gg),   ov = sigmoidf_(go);
        cst = fv * cst + iv * gv;
        float h = ov * tanhf_(cst);
        hlast = h;
        if (kh == 0) {
            outb[(size_t)tt * 256] = (t0 + tt < len) ? h : 0.0f;
            hs[(tt & 1) ^ 1][c + ((c >> 7) << 4)] = __float2half(h);
        }
        __syncthreads();
    }
    if (kh == 0) {
        h_state[b * 256 + c] = __float2half(hlast);
        c_state[b * 256 + c] = cst;
    }
}

// Fallback (ws too small for any xg chunk): fused, streams both fp16 matrices.
__global__ __launch_bounds__(1024) void lstm_fused16(const float* __restrict__ X,
                                                     const __half* __restrict__ Wi16,
                                                     const __half* __restrict__ Wh16,
                                                     const float* __restrict__ bias_p,
                                                     const int* __restrict__ x_len,
                                                     float* __restrict__ out) {
    __shared__ __half hs_h[256];
    __shared__ __half xs_h[256];
    __shared__ float4 part[3][256];
    int tid = threadIdx.x;
    int c = tid & 255, kh = tid >> 8;
    int b = blockIdx.x;
    int len = x_len[b];
    float cst = 0.0f;
    float4 bias;
    if (kh == 0) {
        bias = *(const float4*)&bias_p[4 * c];
        hs_h[c] = __float2half(0.0f);
    }
    const uint4* wph = (const uint4*)(Wh16 + (size_t)(kh * 32) * 2048 + 8 * c);
    const uint4* wpi = (const uint4*)(Wi16 + (size_t)(kh * 32) * 2048 + 8 * c);
    float* outb = out + (size_t)b * 512 * 256 + c;
    __syncthreads();

    for (int t = 0; t < TT; ++t) {
        if (tid < 128) {
            float2 xv = *(const float2*)&X[((size_t)b * 512 + t) * 256 + 2 * tid];
            h2_t xh = {(_Float16)xv.x, (_Float16)xv.y};
            ((h2_t*)xs_h)[tid] = xh;
        }
        __syncthreads();
        float4 acc = {0.0f, 0.0f, 0.0f, 0.0f};
#pragma unroll 4
        for (int i = 0; i < 32; ++i) {
            uint4 uh = wph[(size_t)i * 256];
            uint4 ui = wpi[(size_t)i * 256];
            h2_t hv = ((const h2_t*)hs_h)[kh * 32 + i];
            h2_t xv = ((const h2_t*)xs_h)[kh * 32 + i];
            dot4_(acc, uh, hv);
            dot4_(acc, ui, xv);
        }
        if (kh) part[kh - 1][c] = acc;
        __syncthreads();
        if (kh == 0) {
            float4 p0 = part[0][c], p1 = part[1][c], p2 = part[2][c];
            float gi = acc.x + p0.x + p1.x + p2.x + bias.x;
            float gf = acc.y + p0.y + p1.y + p2.y + bias.y;
            float gg = acc.z + p0.z + p1.z + p2.z + bias.z;
            float go = acc.w + p0.w + p1.w + p2.w + bias.w;
            float iv = sigmoidf_(gi), fv = sigmoidf_(gf);
            float gv = tanhf_(gg),   ov = sigmoidf_(go);
            cst = fv * cst + iv * gv;
            float h = ov * tanhf_(cst);
            outb[(size_t)t * 256] = (t < len) ? h : 0.0f;
            hs_h[c] = __float2half(h);
        }
        __syncthreads();
    }
}

extern "C" void kernel_launch(void* const* d_in, const int* in_sizes, int n_in,
                              void* d_out, int out_size, void* d_ws, size_t ws_size,
                              hipStream_t stream) {
    const float* x     = (const float*)d_in[0];
    const int*   x_len = (const int*)d_in[1];
    const float* W_ih  = (const float*)d_in[2];
    const float* W_hh  = (const float*)d_in[3];
    const float* b_ih  = (const float*)d_in[4];
    const float* b_hh  = (const float*)d_in[5];
    float* out = (float*)d_out;

    char* ws = (char*)d_ws;
    __half* Wh16    = (__half*)(ws);                      // 512 KB
    __half* Wi16    = (__half*)(ws + 0x080000);           // 512 KB
    __half* Wg16    = (__half*)(ws + 0x100000);           // 512 KB
    float*  bias_p  = (float*)(ws + 0x180000);            // 4 KB
    __half* h_state = (__half*)(ws + 0x181000);           // 64 KB
    float*  c_state = (float*)(ws + 0x191000);            // 128 KB
    __half* x16     = (__half*)(ws + 0x1B1000);           // 33.6 MB
    size_t  o_xg    = 0x1B1000 + (size_t)0x2004000;
    __half* xg      = (__half*)(ws + o_xg);

    int Tc = 0;
    for (int cand = 512; cand >= 16; cand >>= 1)
        if (ws_size >= o_xg + (size_t)cand * 262144) { Tc = cand; break; }

    pack2<<<1024, 256, 0, stream>>>(W_ih, W_hh, b_ih, b_hh,
                                    Wg16, Wi16, Wh16, bias_p);
    if (Tc) {
        cvt_x<<<8192, 256, 0, stream>>>(x, x16);
        int lTc = 31 - __builtin_clz((unsigned)Tc);
        for (int t0 = 0; t0 < TT; t0 += Tc) {
            dim3 g(2 * Tc, 16);   // (128*Tc/64, 1024/64)
            xg_gemm_mfma<<<g, 256, 0, stream>>>(x16, Wg16, bias_p, xg,
                                                t0, lTc, Tc - 1);
            lstm_rec4<<<BB, 512, 0, stream>>>(xg, Wh16, x_len, out,
                                              h_state, c_state, t0, Tc);
        }
    } else {
        lstm_fused16<<<BB, 1024, 0, stream>>>(x, Wi16, Wh16, bias_p, x_len, out);
    }
}

// Round 8
// 1511.239 us; speedup vs baseline: 2.7590x; 2.7590x over previous
//
#include <hip/hip_runtime.h>
#include <hip/hip_fp16.h>
#include <math.h>

#define BB 128
#define TT 512
#define DD 256
#define HH 256
#define NG 1024  // 4*H

typedef _Float16 h2_t __attribute__((ext_vector_type(2)));
typedef _Float16 f16x8 __attribute__((ext_vector_type(8)));
typedef float f32x4 __attribute__((ext_vector_type(4)));

#if __has_builtin(__builtin_amdgcn_fdot2)
__device__ __forceinline__ float fdot2_(h2_t a, h2_t b, float c) {
    return __builtin_amdgcn_fdot2(a, b, c, false);
}
#else
__device__ __forceinline__ float fdot2_(h2_t a, h2_t b, float c) {
    return c + (float)a.x * (float)b.x + (float)a.y * (float)b.y;
}
#endif

__device__ __forceinline__ float sigmoidf_(float x) {
    return 1.0f / (1.0f + __expf(-x));
}
__device__ __forceinline__ float tanhf_(float x) {
    x = fminf(15.0f, fmaxf(-15.0f, x));
    float e = __expf(2.0f * x);
    return (e - 1.0f) / (e + 1.0f);
}
__device__ __forceinline__ void dot4_(float4& acc, uint4 u, h2_t h) {
    acc.x = fdot2_(__builtin_bit_cast(h2_t, u.x), h, acc.x);
    acc.y = fdot2_(__builtin_bit_cast(h2_t, u.y), h, acc.y);
    acc.z = fdot2_(__builtin_bit_cast(h2_t, u.z), h, acc.z);
    acc.w = fdot2_(__builtin_bit_cast(h2_t, u.w), h, acc.w);
}

// AGPR-resident value read as one full-rate VALU op. NON-volatile (R3's
// volatile chain serialized the loop) with a dummy loop-variant operand
// (dep = tt): LICM cannot hoist the reads out of the timestep loop, but the
// scheduler remains free to interleave them with the dot2s.
__device__ __forceinline__ uint ar_(const uint& a, int dep) {
    uint v;
    asm("v_accvgpr_read_b32 %0, %1" : "=v"(v) : "a"(a), "v"(dep));
    return v;
}

// Pair sum across lanes (l, l^1) via DPP quad_perm [1,0,3,2] — VALU pipe.
#if __has_builtin(__builtin_amdgcn_update_dpp)
__device__ __forceinline__ float pair_sum_(float v) {
    int x = __builtin_bit_cast(int, v);
    int y = __builtin_amdgcn_update_dpp(0, x, 0xB1, 0xF, 0xF, true);
    return v + __builtin_bit_cast(float, y);
}
#else
__device__ __forceinline__ float pair_sum_(float v) {
    return v + __shfl_xor(v, 1, 64);
}
#endif

// Pack: packed col n = j*4+q <-> gate row g = q*256+j  (q: 0=i,1=f,2=g,3=o)
//  Wg16 [n][k] fp16            (MFMA GEMM B operand)
//  Wi16/Wh16 fp16 k-pair-major (halfs at ((k>>1)*1024 + n)*2 + (k&1))
//  bias_p[n] = b_ih[g] + b_hh[g]
__global__ void pack2(const float* __restrict__ W_ih, const float* __restrict__ W_hh,
                      const float* __restrict__ b_ih, const float* __restrict__ b_hh,
                      __half* __restrict__ Wg16, __half* __restrict__ Wi16,
                      __half* __restrict__ Wh16, float* __restrict__ bias_p) {
    int idx = blockIdx.x * 256 + threadIdx.x;   // 0..262143
    int n = idx >> 8;
    int k = idx & 255;
    int g = (n & 3) * 256 + (n >> 2);
    float wih = W_ih[g * 256 + k];
    float whh = W_hh[g * 256 + k];
    Wg16[n * 256 + k] = __float2half(wih);
    size_t hidx = ((size_t)(k >> 1) * 1024 + n) * 2 + (k & 1);
    Wi16[hidx] = __float2half(wih);
    Wh16[hidx] = __float2half(whh);
    if (idx < 1024) {
        int gg = (idx & 3) * 256 + (idx >> 2);
        bias_p[idx] = b_ih[gg] + b_hh[gg];
    }
}

// x fp32 -> fp16, 8 elements/thread
__global__ __launch_bounds__(256) void cvt_x(const float* __restrict__ X,
                                             __half* __restrict__ X16) {
    size_t i = ((size_t)blockIdx.x * 256 + threadIdx.x) * 8;
    float4 a = *(const float4*)&X[i];
    float4 b = *(const float4*)&X[i + 4];
    f16x8 v;
    v[0] = (_Float16)a.x; v[1] = (_Float16)a.y; v[2] = (_Float16)a.z; v[3] = (_Float16)a.w;
    v[4] = (_Float16)b.x; v[5] = (_Float16)b.y; v[6] = (_Float16)b.z; v[7] = (_Float16)b.w;
    *(f16x8*)&X16[i] = v;
}

// xg chunk GEMM via MFMA f16: M = 128*Tc, N = 1024, K = 256.
__global__ __launch_bounds__(256) void xg_gemm_mfma(const __half* __restrict__ X16,
                                                    const __half* __restrict__ Wg16,
                                                    const float* __restrict__ bias_p,
                                                    __half* __restrict__ xg,
                                                    int t0, int lTc, int tcMask) {
    __shared__ __align__(16) __half st[4][16][72];
    int tid = threadIdx.x;
    int w = tid >> 6, lane = tid & 63;
    int row16 = lane & 15, quad = lane >> 4;
    int m0 = blockIdx.x * 64 + w * 16;
    int n0 = blockIdx.y * 64;

    int mrow = m0 + row16;                                   // chunk-local row
    size_t xrow = (size_t)(mrow >> lTc) * 512 + t0 + (mrow & tcMask);
    const __half* aptr = X16 + xrow * 256 + quad * 8;
    f16x8 afrag[8];
#pragma unroll
    for (int kk = 0; kk < 8; ++kk)
        afrag[kk] = *(const f16x8*)(aptr + kk * 32);

#pragma unroll
    for (int cg = 0; cg < 4; ++cg) {
        int n = n0 + cg * 16 + row16;
        const __half* bptr = Wg16 + (size_t)n * 256 + quad * 8;
        f32x4 acc = {0.0f, 0.0f, 0.0f, 0.0f};
#pragma unroll
        for (int kk = 0; kk < 8; ++kk) {
            f16x8 bfrag = *(const f16x8*)(bptr + kk * 32);
            acc = __builtin_amdgcn_mfma_f32_16x16x32_f16(afrag[kk], bfrag, acc, 0, 0, 0);
        }
        float bias = bias_p[n];
#pragma unroll
        for (int r = 0; r < 4; ++r)
            st[w][quad * 4 + r][cg * 16 + row16] = __float2half(acc[r] + bias);
    }
    __syncthreads();
    int ml = lane >> 2, cq = lane & 3;
    int mout = blockIdx.x * 64 + w * 16 + ml;                // chunk-local row
    const uint4* src = (const uint4*)&st[w][ml][cq * 16];
    uint4 v0 = src[0], v1 = src[1];
    *(uint4*)&xg[(size_t)mout * 1024 + n0 + cq * 16] = v0;
    *(uint4*)&xg[(size_t)mout * 1024 + n0 + cq * 16 + 8] = v1;
}

// Recurrence v9 = R6 structure + R3's proven AGPR allocation + R7's
// schedulable reads, sized INSIDE the unified 256-reg budget (R7's lesson:
// AGPR + arch share one file; 192+128 = 320 spilled).
// Thread (c = tid>>1, kh = tid&1): 4 gates of col c, k-half kh (64 k-pairs).
// Residency:
//   k-pairs  0..19 : wreg[20] arch VGPR (80 regs; arch live ~110 < 128 left
//                    beside the AGPRs -> below remat threshold)
//   k-pairs 20..51 : 128 AGPRs (R3/R4-proven allocatable), read in-loop via
//                    non-volatile tt-dependent v_accvgpr_read (2-cyc VALU,
//                    schedulable, un-hoistable)
//   k-pairs 52..63 : LDS, 12 k-pairs, 96 KB, sequential [i][tid] layout
//                    (R2-verified conflict-free)
// Zero per-step weight VMEM (R6 remat'd ~196 KB/step through L1 - that was
// the 3100-cyc bottleneck). hs padded [2][272] (R3-verified conflicts -> 0).
__global__ __launch_bounds__(512, 2) void lstm_rec4(const __half* __restrict__ xg,
                                                    const __half* __restrict__ Wh16,
                                                    const int* __restrict__ x_len,
                                                    float* __restrict__ out,
                                                    __half* __restrict__ h_state,
                                                    float* __restrict__ c_state,
                                                    int t0, int Tc) {
    __shared__ __align__(16) uint4 lw[6144];        // [i<12][c<256][kh<2] : 96 KB
    __shared__ __align__(16) __half hs[2][272];     // padded double-buffered h
    int tid = threadIdx.x;
    int c = tid >> 1, kh = tid & 1;
    int b = blockIdx.x;
    int len = x_len[b];
    const uint4* W4 = (const uint4*)Wh16;           // index: p*256 + c  (p = k-pair)

    // LDS fill: element j = i*512 + c2*2 + kh2 <- k-pair (kh2*64 + 52 + i), col c2
    for (int j = tid; j < 6144; j += 512) {
        int i2 = j >> 9, c2 = (j >> 1) & 255, kh2 = j & 1;
        lw[j] = W4[(size_t)(kh2 * 64 + 52 + i2) * 256 + c2];
    }
    const uint4* wp = W4 + (size_t)(kh * 64) * 256 + c;
    // k-pairs 0..19 in arch VGPRs (allocator-managed, below remat threshold)
    uint4 wreg[20];
#pragma unroll
    for (int i = 0; i < 20; ++i) wreg[i] = wp[(size_t)i * 256];
    // k-pairs 20..51 in AGPRs (pinned; asm results cannot be rematerialized)
    uint4 wa4[32];
#pragma unroll
    for (int i = 0; i < 32; ++i) wa4[i] = wp[(size_t)(20 + i) * 256];
#pragma unroll
    for (int i = 0; i < 32; ++i)
        asm volatile("" : "+a"(wa4[i].x), "+a"(wa4[i].y),
                          "+a"(wa4[i].z), "+a"(wa4[i].w));

    float cst = 0.0f;
    float hlast = 0.0f;
    if (t0 != 0) cst = c_state[b * 256 + c];        // replicated in both lanes
    if (kh == 0)
        hs[0][c + ((c >> 7) << 4)] = (t0 == 0) ? __float2half(0.0f)
                                               : h_state[b * 256 + c];

    const __half* xgb = xg + (size_t)b * Tc * 1024 + 4 * c;
    float* outb = out + ((size_t)b * 512 + t0) * 256 + c;
    const uint4* lwb = lw + tid;                    // [i*512] strides
    __syncthreads();

    for (int tt = 0; tt < Tc; ++tt) {
        uint2 xr = *(const uint2*)(xgb + (size_t)tt * 1024);

        // kh-half base: kh=0 -> uint4 idx 0, kh=1 -> idx 18 (byte 288)
        const uint4* h4 = (const uint4*)(hs[tt & 1]) + kh * 18;
        float4 acc = {0.0f, 0.0f, 0.0f, 0.0f};
        // j = 0..4: k-pairs 0..19 in arch VGPRs
#pragma unroll
        for (int j = 0; j < 5; ++j) {
            uint4 hv = h4[j];
            dot4_(acc, wreg[j * 4 + 0], __builtin_bit_cast(h2_t, hv.x));
            dot4_(acc, wreg[j * 4 + 1], __builtin_bit_cast(h2_t, hv.y));
            dot4_(acc, wreg[j * 4 + 2], __builtin_bit_cast(h2_t, hv.z));
            dot4_(acc, wreg[j * 4 + 3], __builtin_bit_cast(h2_t, hv.w));
        }
        // j = 5..12: k-pairs 20..51 in AGPRs
#define DOT4A(ai, hx)                                                          \
        {                                                                      \
            h2_t hh = __builtin_bit_cast(h2_t, hx);                            \
            acc.x = fdot2_(__builtin_bit_cast(h2_t, ar_(wa4[ai].x, tt)), hh, acc.x); \
            acc.y = fdot2_(__builtin_bit_cast(h2_t, ar_(wa4[ai].y, tt)), hh, acc.y); \
            acc.z = fdot2_(__builtin_bit_cast(h2_t, ar_(wa4[ai].z, tt)), hh, acc.z); \
            acc.w = fdot2_(__builtin_bit_cast(h2_t, ar_(wa4[ai].w, tt)), hh, acc.w); \
        }
#pragma unroll
        for (int j = 5; j < 13; ++j) {
            uint4 hv = h4[j];
            int a0 = (j - 5) * 4;
            DOT4A(a0 + 0, hv.x);
            DOT4A(a0 + 1, hv.y);
            DOT4A(a0 + 2, hv.z);
            DOT4A(a0 + 3, hv.w);
        }
#undef DOT4A
        // j = 13..15: k-pairs 52..63 from LDS (i = 0..11)
#pragma unroll
        for (int j = 13; j < 16; ++j) {
            uint4 hv = h4[j];
            int i0 = (j - 13) * 4;
            dot4_(acc, lwb[(i0 + 0) * 512], __builtin_bit_cast(h2_t, hv.x));
            dot4_(acc, lwb[(i0 + 1) * 512], __builtin_bit_cast(h2_t, hv.y));
            dot4_(acc, lwb[(i0 + 2) * 512], __builtin_bit_cast(h2_t, hv.z));
            dot4_(acc, lwb[(i0 + 3) * 512], __builtin_bit_cast(h2_t, hv.w));
        }
        // reduce partials over kh (lanes l, l^1) on the VALU pipe
        float gi = pair_sum_(acc.x);
        float gf = pair_sum_(acc.y);
        float gg = pair_sum_(acc.z);
        float go = pair_sum_(acc.w);
        h2_t x01 = __builtin_bit_cast(h2_t, xr.x);
        h2_t x23 = __builtin_bit_cast(h2_t, xr.y);
        gi += (float)x01.x;
        gf += (float)x01.y;
        gg += (float)x23.x;
        go += (float)x23.y;
        // gate math: both lanes redundantly (identical inputs -> identical cst)
        float iv = sigmoidf_(gi), fv = sigmoidf_(gf);
        float gv = tanhf_(gg),   ov = sigmoidf_(go);
        cst = fv * cst + iv * gv;
        float h = ov * tanhf_(cst);
        hlast = h;
        if (kh == 0) {
            outb[(size_t)tt * 256] = (t0 + tt < len) ? h : 0.0f;
            hs[(tt & 1) ^ 1][c + ((c >> 7) << 4)] = __float2half(h);
        }
        __syncthreads();
    }
    if (kh == 0) {
        h_state[b * 256 + c] = __float2half(hlast);
        c_state[b * 256 + c] = cst;
    }
}

// Fallback (ws too small for any xg chunk): fused, streams both fp16 matrices.
__global__ __launch_bounds__(1024) void lstm_fused16(const float* __restrict__ X,
                                                     const __half* __restrict__ Wi16,
                                                     const __half* __restrict__ Wh16,
                                                     const float* __restrict__ bias_p,
                                                     const int* __restrict__ x_len,
                                                     float* __restrict__ out) {
    __shared__ __half hs_h[256];
    __shared__ __half xs_h[256];
    __shared__ float4 part[3][256];
    int tid = threadIdx.x;
    int c = tid & 255, kh = tid >> 8;
    int b = blockIdx.x;
    int len = x_len[b];
    float cst = 0.0f;
    float4 bias;
    if (kh == 0) {
        bias = *(const float4*)&bias_p[4 * c];
        hs_h[c] = __float2half(0.0f);
    }
    const uint4* wph = (const uint4*)(Wh16 + (size_t)(kh * 32) * 2048 + 8 * c);
    const uint4* wpi = (const uint4*)(Wi16 + (size_t)(kh * 32) * 2048 + 8 * c);
    float* outb = out + (size_t)b * 512 * 256 + c;
    __syncthreads();

    for (int t = 0; t < TT; ++t) {
        if (tid < 128) {
            float2 xv = *(const float2*)&X[((size_t)b * 512 + t) * 256 + 2 * tid];
            h2_t xh = {(_Float16)xv.x, (_Float16)xv.y};
            ((h2_t*)xs_h)[tid] = xh;
        }
        __syncthreads();
        float4 acc = {0.0f, 0.0f, 0.0f, 0.0f};
#pragma unroll 4
        for (int i = 0; i < 32; ++i) {
            uint4 uh = wph[(size_t)i * 256];
            uint4 ui = wpi[(size_t)i * 256];
            h2_t hv = ((const h2_t*)hs_h)[kh * 32 + i];
            h2_t xv = ((const h2_t*)xs_h)[kh * 32 + i];
            dot4_(acc, uh, hv);
            dot4_(acc, ui, xv);
        }
        if (kh) part[kh - 1][c] = acc;
        __syncthreads();
        if (kh == 0) {
            float4 p0 = part[0][c], p1 = part[1][c], p2 = part[2][c];
            float gi = acc.x + p0.x + p1.x + p2.x + bias.x;
            float gf = acc.y + p0.y + p1.y + p2.y + bias.y;
            float gg = acc.z + p0.z + p1.z + p2.z + bias.z;
            float go = acc.w + p0.w + p1.w + p2.w + bias.w;
            float iv = sigmoidf_(gi), fv = sigmoidf_(gf);
            float gv = tanhf_(gg),   ov = sigmoidf_(go);
            cst = fv * cst + iv * gv;
            float h = ov * tanhf_(cst);
            outb[(size_t)t * 256] = (t < len) ? h : 0.0f;
            hs_h[c] = __float2half(h);
        }
        __syncthreads();
    }
}

extern "C" void kernel_launch(void* const* d_in, const int* in_sizes, int n_in,
                              void* d_out, int out_size, void* d_ws, size_t ws_size,
                              hipStream_t stream) {
    const float* x     = (const float*)d_in[0];
    const int*   x_len = (const int*)d_in[1];
    const float* W_ih  = (const float*)d_in[2];
    const float* W_hh  = (const float*)d_in[3];
    const float* b_ih  = (const float*)d_in[4];
    const float* b_hh  = (const float*)d_in[5];
    float* out = (float*)d_out;

    char* ws = (char*)d_ws;
    __half* Wh16    = (__half*)(ws);                      // 512 KB
    __half* Wi16    = (__half*)(ws + 0x080000);           // 512 KB
    __half* Wg16    = (__half*)(ws + 0x100000);           // 512 KB
    float*  bias_p  = (float*)(ws + 0x180000);            // 4 KB
    __half* h_state = (__half*)(ws + 0x181000);           // 64 KB
    float*  c_state = (float*)(ws + 0x191000);            // 128 KB
    __half* x16     = (__half*)(ws + 0x1B1000);           // 33.6 MB
    size_t  o_xg    = 0x1B1000 + (size_t)0x2004000;
    __half* xg      = (__half*)(ws + o_xg);

    int Tc = 0;
    for (int cand = 512; cand >= 16; cand >>= 1)
        if (ws_size >= o_xg + (size_t)cand * 262144) { Tc = cand; break; }

    pack2<<<1024, 256, 0, stream>>>(W_ih, W_hh, b_ih, b_hh,
                                    Wg16, Wi16, Wh16, bias_p);
    if (Tc) {
        cvt_x<<<8192, 256, 0, stream>>>(x, x16);
        int lTc = 31 - __builtin_clz((unsigned)Tc);
        for (int t0 = 0; t0 < TT; t0 += Tc) {
            dim3 g(2 * Tc, 16);   // (128*Tc/64, 1024/64)
            xg_gemm_mfma<<<g, 256, 0, stream>>>(x16, Wg16, bias_p, xg,
                                                t0, lTc, Tc - 1);
            lstm_rec4<<<BB, 512, 0, stream>>>(xg, Wh16, x_len, out,
                                              h_state, c_state, t0, Tc);
        }
    } else {
        lstm_fused16<<<BB, 1024, 0, stream>>>(x, Wi16, Wh16, bias_p, x_len, out);
    }
}

// Round 9
// 1492.532 us; speedup vs baseline: 2.7936x; 1.0125x over previous
//
#include <hip/hip_runtime.h>
#include <hip/hip_fp16.h>
#include <math.h>

#define BB 128
#define TT 512
#define DD 256
#define HH 256
#define NG 1024  // 4*H

typedef _Float16 h2_t __attribute__((ext_vector_type(2)));
typedef _Float16 f16x8 __attribute__((ext_vector_type(8)));
typedef float f32x4 __attribute__((ext_vector_type(4)));

#if __has_builtin(__builtin_amdgcn_fdot2)
__device__ __forceinline__ float fdot2_(h2_t a, h2_t b, float c) {
    return __builtin_amdgcn_fdot2(a, b, c, false);
}
#else
__device__ __forceinline__ float fdot2_(h2_t a, h2_t b, float c) {
    return c + (float)a.x * (float)b.x + (float)a.y * (float)b.y;
}
#endif

__device__ __forceinline__ float sigmoidf_(float x) {
    return 1.0f / (1.0f + __expf(-x));
}
__device__ __forceinline__ float tanhf_(float x) {
    x = fminf(15.0f, fmaxf(-15.0f, x));
    float e = __expf(2.0f * x);
    return (e - 1.0f) / (e + 1.0f);
}
__device__ __forceinline__ void dot4_(float4& acc, uint4 u, h2_t h) {
    acc.x = fdot2_(__builtin_bit_cast(h2_t, u.x), h, acc.x);
    acc.y = fdot2_(__builtin_bit_cast(h2_t, u.y), h, acc.y);
    acc.z = fdot2_(__builtin_bit_cast(h2_t, u.z), h, acc.z);
    acc.w = fdot2_(__builtin_bit_cast(h2_t, u.w), h, acc.w);
}

// Sum across the 4 lanes of a quad (kq = lane&3) via two DPP quad_perms
// (xor1 = [1,0,3,2] = 0xB1, xor2 = [2,3,0,1] = 0x4E). Pure VALU, full-rate,
// no LDS traffic, no barrier. All 4 lanes end with the total.
#if __has_builtin(__builtin_amdgcn_update_dpp)
__device__ __forceinline__ float quad_sum_(float v) {
    int x = __builtin_bit_cast(int, v);
    int y = __builtin_amdgcn_update_dpp(0, x, 0xB1, 0xF, 0xF, true);
    float s = v + __builtin_bit_cast(float, y);
    int x2 = __builtin_bit_cast(int, s);
    int y2 = __builtin_amdgcn_update_dpp(0, x2, 0x4E, 0xF, 0xF, true);
    return s + __builtin_bit_cast(float, y2);
}
#else
__device__ __forceinline__ float quad_sum_(float v) {
    float s = v + __shfl_xor(v, 1, 64);
    return s + __shfl_xor(s, 2, 64);
}
#endif

// Pack: packed col n = j*4+q <-> gate row g = q*256+j  (q: 0=i,1=f,2=g,3=o)
//  Wg16 [n][k] fp16            (MFMA GEMM B operand)
//  Wi16/Wh16 fp16 k-pair-major (halfs at ((k>>1)*1024 + n)*2 + (k&1))
//  bias_p[n] = b_ih[g] + b_hh[g]
__global__ void pack2(const float* __restrict__ W_ih, const float* __restrict__ W_hh,
                      const float* __restrict__ b_ih, const float* __restrict__ b_hh,
                      __half* __restrict__ Wg16, __half* __restrict__ Wi16,
                      __half* __restrict__ Wh16, float* __restrict__ bias_p) {
    int idx = blockIdx.x * 256 + threadIdx.x;   // 0..262143
    int n = idx >> 8;
    int k = idx & 255;
    int g = (n & 3) * 256 + (n >> 2);
    float wih = W_ih[g * 256 + k];
    float whh = W_hh[g * 256 + k];
    Wg16[n * 256 + k] = __float2half(wih);
    size_t hidx = ((size_t)(k >> 1) * 1024 + n) * 2 + (k & 1);
    Wi16[hidx] = __float2half(wih);
    Wh16[hidx] = __float2half(whh);
    if (idx < 1024) {
        int gg = (idx & 3) * 256 + (idx >> 2);
        bias_p[idx] = b_ih[gg] + b_hh[gg];
    }
}

// x fp32 -> fp16, 8 elements/thread
__global__ __launch_bounds__(256) void cvt_x(const float* __restrict__ X,
                                             __half* __restrict__ X16) {
    size_t i = ((size_t)blockIdx.x * 256 + threadIdx.x) * 8;
    float4 a = *(const float4*)&X[i];
    float4 b = *(const float4*)&X[i + 4];
    f16x8 v;
    v[0] = (_Float16)a.x; v[1] = (_Float16)a.y; v[2] = (_Float16)a.z; v[3] = (_Float16)a.w;
    v[4] = (_Float16)b.x; v[5] = (_Float16)b.y; v[6] = (_Float16)b.z; v[7] = (_Float16)b.w;
    *(f16x8*)&X16[i] = v;
}

// xg chunk GEMM via MFMA f16: M = 128*Tc, N = 1024, K = 256.
__global__ __launch_bounds__(256) void xg_gemm_mfma(const __half* __restrict__ X16,
                                                    const __half* __restrict__ Wg16,
                                                    const float* __restrict__ bias_p,
                                                    __half* __restrict__ xg,
                                                    int t0, int lTc, int tcMask) {
    __shared__ __align__(16) __half st[4][16][72];
    int tid = threadIdx.x;
    int w = tid >> 6, lane = tid & 63;
    int row16 = lane & 15, quad = lane >> 4;
    int m0 = blockIdx.x * 64 + w * 16;
    int n0 = blockIdx.y * 64;

    int mrow = m0 + row16;                                   // chunk-local row
    size_t xrow = (size_t)(mrow >> lTc) * 512 + t0 + (mrow & tcMask);
    const __half* aptr = X16 + xrow * 256 + quad * 8;
    f16x8 afrag[8];
#pragma unroll
    for (int kk = 0; kk < 8; ++kk)
        afrag[kk] = *(const f16x8*)(aptr + kk * 32);

#pragma unroll
    for (int cg = 0; cg < 4; ++cg) {
        int n = n0 + cg * 16 + row16;
        const __half* bptr = Wg16 + (size_t)n * 256 + quad * 8;
        f32x4 acc = {0.0f, 0.0f, 0.0f, 0.0f};
#pragma unroll
        for (int kk = 0; kk < 8; ++kk) {
            f16x8 bfrag = *(const f16x8*)(bptr + kk * 32);
            acc = __builtin_amdgcn_mfma_f32_16x16x32_f16(afrag[kk], bfrag, acc, 0, 0, 0);
        }
        float bias = bias_p[n];
#pragma unroll
        for (int r = 0; r < 4; ++r)
            st[w][quad * 4 + r][cg * 16 + row16] = __float2half(acc[r] + bias);
    }
    __syncthreads();
    int ml = lane >> 2, cq = lane & 3;
    int mout = blockIdx.x * 64 + w * 16 + ml;                // chunk-local row
    const uint4* src = (const uint4*)&st[w][ml][cq * 16];
    uint4 v0 = src[0], v1 = src[1];
    *(uint4*)&xg[(size_t)mout * 1024 + n0 + cq * 16] = v0;
    *(uint4*)&xg[(size_t)mout * 1024 + n0 + cq * 16 + 8] = v1;
}

// Recurrence v10: 128 blocks x 1024 threads (16 waves -> 4 waves/SIMD).
// Cross-round ledger: every 512-thread variant pins at VALUBusy ~37%,
// stall ~63% — ~170-200 KB/step of weights must stream from L1/L2 (the CU
// regfile is 512 KB total = exactly W_hh's size; full residency impossible)
// and 2 waves/SIMD can't hide that latency. v10 keeps R6's residency
// economics but doubles TLP: thread (c = tid>>2, kq = tid&3) owns 32
// k-pairs; reduction over kq via quad-DPP (no part[] LDS exchange, no 2nd
// barrier, no serial kh0 tail — R0's three defects); gate math redundant
// in all 4 lanes. Residency per thread: k-pairs 0..11 wreg (48 regs),
// 12..19 LDS (128 KB, R2-verified sequential layout), 20..31 streamed in
// three 4-load windows (live regs ~115 <= 128 budget at 4 waves/SIMD).
__global__ __launch_bounds__(1024, 4) void lstm_rec4(const __half* __restrict__ xg,
                                                     const __half* __restrict__ Wh16,
                                                     const int* __restrict__ x_len,
                                                     float* __restrict__ out,
                                                     __half* __restrict__ h_state,
                                                     float* __restrict__ c_state,
                                                     int t0, int Tc) {
    __shared__ __align__(16) uint4 lw[8192];        // [i<8][c<256][kq<4] : 128 KB
    __shared__ __align__(16) __half hs[2][256];     // double-buffered h
    int tid = threadIdx.x;
    int c = tid >> 2, kq = tid & 3;
    int b = blockIdx.x;
    int len = x_len[b];
    const uint4* W4 = (const uint4*)Wh16;           // index: p*256 + c  (p = k-pair)

    // LDS fill: element j = i*1024 + c2*4 + kq2 <- k-pair (kq2*32 + 12 + i), col c2
    for (int j = tid; j < 8192; j += 1024) {
        int i2 = j >> 10, r = j & 1023, c2 = r >> 2, kq2 = r & 3;
        lw[j] = W4[(size_t)(kq2 * 32 + 12 + i2) * 256 + c2];
    }
    const uint4* wp = W4 + (size_t)(kq * 32) * 256 + c;
    // k-pairs kq*32 + 0..11 in arch VGPRs
    uint4 wreg[12];
#pragma unroll
    for (int i = 0; i < 12; ++i) wreg[i] = wp[(size_t)i * 256];

    float cst = 0.0f;
    float hlast = 0.0f;
    if (t0 != 0) cst = c_state[b * 256 + c];        // replicated in 4 lanes
    if (tid < 256)
        hs[0][tid] = (t0 == 0) ? __float2half(0.0f) : h_state[b * 256 + tid];

    const __half* xgb = xg + (size_t)b * Tc * 1024 + 4 * c;
    float* outb = out + ((size_t)b * 512 + t0) * 256 + c;
    const uint4* lwb = lw + tid;                    // [i*1024] strides
    __syncthreads();

    for (int tt = 0; tt < Tc; ++tt) {
        // stream window A: k-pairs 20..23 (consumed at j=5)
        uint4 sA0 = wp[(size_t)20 * 256];
        uint4 sA1 = wp[(size_t)21 * 256];
        uint4 sA2 = wp[(size_t)22 * 256];
        uint4 sA3 = wp[(size_t)23 * 256];
        uint2 xr = *(const uint2*)(xgb + (size_t)tt * 1024);

        // this thread's h slice: halfs [kq*64, kq*64+64) = uint4s kq*8 + 0..7
        const uint4* h4 = (const uint4*)(hs[tt & 1]) + kq * 8;
        float4 acc = {0.0f, 0.0f, 0.0f, 0.0f};
        // j = 0..2: k-pairs 0..11 in wreg
#pragma unroll
        for (int j = 0; j < 3; ++j) {
            uint4 hv = h4[j];
            dot4_(acc, wreg[j * 4 + 0], __builtin_bit_cast(h2_t, hv.x));
            dot4_(acc, wreg[j * 4 + 1], __builtin_bit_cast(h2_t, hv.y));
            dot4_(acc, wreg[j * 4 + 2], __builtin_bit_cast(h2_t, hv.z));
            dot4_(acc, wreg[j * 4 + 3], __builtin_bit_cast(h2_t, hv.w));
        }
        // stream window B: k-pairs 24..27 (consumed at j=6)
        uint4 sB0 = wp[(size_t)24 * 256];
        uint4 sB1 = wp[(size_t)25 * 256];
        uint4 sB2 = wp[(size_t)26 * 256];
        uint4 sB3 = wp[(size_t)27 * 256];
        // j = 3,4: k-pairs 12..19 from LDS (i = 0..7)
        {
            uint4 hv = h4[3];
            dot4_(acc, lwb[0 * 1024], __builtin_bit_cast(h2_t, hv.x));
            dot4_(acc, lwb[1 * 1024], __builtin_bit_cast(h2_t, hv.y));
            dot4_(acc, lwb[2 * 1024], __builtin_bit_cast(h2_t, hv.z));
            dot4_(acc, lwb[3 * 1024], __builtin_bit_cast(h2_t, hv.w));
        }
        // stream window C: k-pairs 28..31 (consumed at j=7)
        uint4 sC0 = wp[(size_t)28 * 256];
        uint4 sC1 = wp[(size_t)29 * 256];
        uint4 sC2 = wp[(size_t)30 * 256];
        uint4 sC3 = wp[(size_t)31 * 256];
        {
            uint4 hv = h4[4];
            dot4_(acc, lwb[4 * 1024], __builtin_bit_cast(h2_t, hv.x));
            dot4_(acc, lwb[5 * 1024], __builtin_bit_cast(h2_t, hv.y));
            dot4_(acc, lwb[6 * 1024], __builtin_bit_cast(h2_t, hv.z));
            dot4_(acc, lwb[7 * 1024], __builtin_bit_cast(h2_t, hv.w));
        }
        // j = 5..7: streamed k-pairs 20..31
        {
            uint4 hv = h4[5];
            dot4_(acc, sA0, __builtin_bit_cast(h2_t, hv.x));
            dot4_(acc, sA1, __builtin_bit_cast(h2_t, hv.y));
            dot4_(acc, sA2, __builtin_bit_cast(h2_t, hv.z));
            dot4_(acc, sA3, __builtin_bit_cast(h2_t, hv.w));
        }
        {
            uint4 hv = h4[6];
            dot4_(acc, sB0, __builtin_bit_cast(h2_t, hv.x));
            dot4_(acc, sB1, __builtin_bit_cast(h2_t, hv.y));
            dot4_(acc, sB2, __builtin_bit_cast(h2_t, hv.z));
            dot4_(acc, sB3, __builtin_bit_cast(h2_t, hv.w));
        }
        {
            uint4 hv = h4[7];
            dot4_(acc, sC0, __builtin_bit_cast(h2_t, hv.x));
            dot4_(acc, sC1, __builtin_bit_cast(h2_t, hv.y));
            dot4_(acc, sC2, __builtin_bit_cast(h2_t, hv.z));
            dot4_(acc, sC3, __builtin_bit_cast(h2_t, hv.w));
        }
        // reduce partials over kq (quad lanes) on the VALU pipe
        float gi = quad_sum_(acc.x);
        float gf = quad_sum_(acc.y);
        float gg = quad_sum_(acc.z);
        float go = quad_sum_(acc.w);
        h2_t x01 = __builtin_bit_cast(h2_t, xr.x);
        h2_t x23 = __builtin_bit_cast(h2_t, xr.y);
        gi += (float)x01.x;
        gf += (float)x01.y;
        gg += (float)x23.x;
        go += (float)x23.y;
        // gate math: all 4 lanes redundantly (identical inputs/results)
        float iv = sigmoidf_(gi), fv = sigmoidf_(gf);
        float gv = tanhf_(gg),   ov = sigmoidf_(go);
        cst = fv * cst + iv * gv;
        float h = ov * tanhf_(cst);
        hlast = h;
        if (kq == 0) {
            outb[(size_t)tt * 256] = (t0 + tt < len) ? h : 0.0f;
            hs[(tt & 1) ^ 1][c] = __float2half(h);
        }
        __syncthreads();
    }
    if (kq == 0) {
        h_state[b * 256 + c] = __float2half(hlast);
        c_state[b * 256 + c] = cst;
    }
}

// Fallback (ws too small for any xg chunk): fused, streams both fp16 matrices.
__global__ __launch_bounds__(1024) void lstm_fused16(const float* __restrict__ X,
                                                     const __half* __restrict__ Wi16,
                                                     const __half* __restrict__ Wh16,
                                                     const float* __restrict__ bias_p,
                                                     const int* __restrict__ x_len,
                                                     float* __restrict__ out) {
    __shared__ __half hs_h[256];
    __shared__ __half xs_h[256];
    __shared__ float4 part[3][256];
    int tid = threadIdx.x;
    int c = tid & 255, kh = tid >> 8;
    int b = blockIdx.x;
    int len = x_len[b];
    float cst = 0.0f;
    float4 bias;
    if (kh == 0) {
        bias = *(const float4*)&bias_p[4 * c];
        hs_h[c] = __float2half(0.0f);
    }
    const uint4* wph = (const uint4*)(Wh16 + (size_t)(kh * 32) * 2048 + 8 * c);
    const uint4* wpi = (const uint4*)(Wi16 + (size_t)(kh * 32) * 2048 + 8 * c);
    float* outb = out + (size_t)b * 512 * 256 + c;
    __syncthreads();

    for (int t = 0; t < TT; ++t) {
        if (tid < 128) {
            float2 xv = *(const float2*)&X[((size_t)b * 512 + t) * 256 + 2 * tid];
            h2_t xh = {(_Float16)xv.x, (_Float16)xv.y};
            ((h2_t*)xs_h)[tid] = xh;
        }
        __syncthreads();
        float4 acc = {0.0f, 0.0f, 0.0f, 0.0f};
#pragma unroll 4
        for (int i = 0; i < 32; ++i) {
            uint4 uh = wph[(size_t)i * 256];
            uint4 ui = wpi[(size_t)i * 256];
            h2_t hv = ((const h2_t*)hs_h)[kh * 32 + i];
            h2_t xv = ((const h2_t*)xs_h)[kh * 32 + i];
            dot4_(acc, uh, hv);
            dot4_(acc, ui, xv);
        }
        if (kh) part[kh - 1][c] = acc;
        __syncthreads();
        if (kh == 0) {
            float4 p0 = part[0][c], p1 = part[1][c], p2 = part[2][c];
            float gi = acc.x + p0.x + p1.x + p2.x + bias.x;
            float gf = acc.y + p0.y + p1.y + p2.y + bias.y;
            float gg = acc.z + p0.z + p1.z + p2.z + bias.z;
            float go = acc.w + p0.w + p1.w + p2.w + bias.w;
            float iv = sigmoidf_(gi), fv = sigmoidf_(gf);
            float gv = tanhf_(gg),   ov = sigmoidf_(go);
            cst = fv * cst + iv * gv;
            float h = ov * tanhf_(cst);
            outb[(size_t)t * 256] = (t < len) ? h : 0.0f;
            hs_h[c] = __float2half(h);
        }
        __syncthreads();
    }
}

extern "C" void kernel_launch(void* const* d_in, const int* in_sizes, int n_in,
                              void* d_out, int out_size, void* d_ws, size_t ws_size,
                              hipStream_t stream) {
    const float* x     = (const float*)d_in[0];
    const int*   x_len = (const int*)d_in[1];
    const float* W_ih  = (const float*)d_in[2];
    const float* W_hh  = (const float*)d_in[3];
    const float* b_ih  = (const float*)d_in[4];
    const float* b_hh  = (const float*)d_in[5];
    float* out = (float*)d_out;

    char* ws = (char*)d_ws;
    __half* Wh16    = (__half*)(ws);                      // 512 KB
    __half* Wi16    = (__half*)(ws + 0x080000);           // 512 KB
    __half* Wg16    = (__half*)(ws + 0x100000);           // 512 KB
    float*  bias_p  = (float*)(ws + 0x180000);            // 4 KB
    __half* h_state = (__half*)(ws + 0x181000);           // 64 KB
    float*  c_state = (float*)(ws + 0x191000);            // 128 KB
    __half* x16     = (__half*)(ws + 0x1B1000);           // 33.6 MB
    size_t  o_xg    = 0x1B1000 + (size_t)0x2004000;
    __half* xg      = (__half*)(ws + o_xg);

    int Tc = 0;
    for (int cand = 512; cand >= 16; cand >>= 1)
        if (ws_size >= o_xg + (size_t)cand * 262144) { Tc = cand; break; }

    pack2<<<1024, 256, 0, stream>>>(W_ih, W_hh, b_ih, b_hh,
                                    Wg16, Wi16, Wh16, bias_p);
    if (Tc) {
        cvt_x<<<8192, 256, 0, stream>>>(x, x16);
        int lTc = 31 - __builtin_clz((unsigned)Tc);
        for (int t0 = 0; t0 < TT; t0 += Tc) {
            dim3 g(2 * Tc, 16);   // (128*Tc/64, 1024/64)
            xg_gemm_mfma<<<g, 256, 0, stream>>>(x16, Wg16, bias_p, xg,
                                                t0, lTc, Tc - 1);
            lstm_rec4<<<BB, 1024, 0, stream>>>(xg, Wh16, x_len, out,
                                               h_state, c_state, t0, Tc);
        }
    } else {
        lstm_fused16<<<BB, 1024, 0, stream>>>(x, Wi16, Wh16, bias_p, x_len, out);
    }
}

// Round 10
// 1193.538 us; speedup vs baseline: 3.4934x; 1.2505x over previous
//
#include <hip/hip_runtime.h>
#include <hip/hip_fp16.h>
#include <math.h>

#define BB 128
#define TT 512
#define DD 256
#define HH 256
#define NG 1024  // 4*H

typedef _Float16 h2_t __attribute__((ext_vector_type(2)));
typedef _Float16 f16x8 __attribute__((ext_vector_type(8)));
typedef float f32x4 __attribute__((ext_vector_type(4)));

#if __has_builtin(__builtin_amdgcn_fdot2)
__device__ __forceinline__ float fdot2_(h2_t a, h2_t b, float c) {
    return __builtin_amdgcn_fdot2(a, b, c, false);
}
#else
__device__ __forceinline__ float fdot2_(h2_t a, h2_t b, float c) {
    return c + (float)a.x * (float)b.x + (float)a.y * (float)b.y;
}
#endif

__device__ __forceinline__ float sigmoidf_(float x) {
    return 1.0f / (1.0f + __expf(-x));
}
__device__ __forceinline__ float tanhf_(float x) {
    x = fminf(15.0f, fmaxf(-15.0f, x));
    float e = __expf(2.0f * x);
    return (e - 1.0f) / (e + 1.0f);
}
__device__ __forceinline__ void dot4_(float4& acc, uint4 u, h2_t h) {
    acc.x = fdot2_(__builtin_bit_cast(h2_t, u.x), h, acc.x);
    acc.y = fdot2_(__builtin_bit_cast(h2_t, u.y), h, acc.y);
    acc.z = fdot2_(__builtin_bit_cast(h2_t, u.z), h, acc.z);
    acc.w = fdot2_(__builtin_bit_cast(h2_t, u.w), h, acc.w);
}

// Pair sum across lanes (l, l^1) via DPP quad_perm [1,0,3,2] — VALU pipe,
// no LDS traffic.
#if __has_builtin(__builtin_amdgcn_update_dpp)
__device__ __forceinline__ float pair_sum_(float v) {
    int x = __builtin_bit_cast(int, v);
    int y = __builtin_amdgcn_update_dpp(0, x, 0xB1, 0xF, 0xF, true);
    return v + __builtin_bit_cast(float, y);
}
#else
__device__ __forceinline__ float pair_sum_(float v) {
    return v + __shfl_xor(v, 1, 64);
}
#endif

// Pack: packed col n = j*4+q <-> gate row g = q*256+j  (q: 0=i,1=f,2=g,3=o)
//  Wg16 [n][k] fp16            (MFMA GEMM B operand)
//  Wi16/Wh16 fp16 k-pair-major (halfs at ((k>>1)*1024 + n)*2 + (k&1))
//  bias_p[n] = b_ih[g] + b_hh[g]
__global__ void pack2(const float* __restrict__ W_ih, const float* __restrict__ W_hh,
                      const float* __restrict__ b_ih, const float* __restrict__ b_hh,
                      __half* __restrict__ Wg16, __half* __restrict__ Wi16,
                      __half* __restrict__ Wh16, float* __restrict__ bias_p) {
    int idx = blockIdx.x * 256 + threadIdx.x;   // 0..262143
    int n = idx >> 8;
    int k = idx & 255;
    int g = (n & 3) * 256 + (n >> 2);
    float wih = W_ih[g * 256 + k];
    float whh = W_hh[g * 256 + k];
    Wg16[n * 256 + k] = __float2half(wih);
    size_t hidx = ((size_t)(k >> 1) * 1024 + n) * 2 + (k & 1);
    Wi16[hidx] = __float2half(wih);
    Wh16[hidx] = __float2half(whh);
    if (idx < 1024) {
        int gg = (idx & 3) * 256 + (idx >> 2);
        bias_p[idx] = b_ih[gg] + b_hh[gg];
    }
}

// x fp32 -> fp16, 8 elements/thread
__global__ __launch_bounds__(256) void cvt_x(const float* __restrict__ X,
                                             __half* __restrict__ X16) {
    size_t i = ((size_t)blockIdx.x * 256 + threadIdx.x) * 8;
    float4 a = *(const float4*)&X[i];
    float4 b = *(const float4*)&X[i + 4];
    f16x8 v;
    v[0] = (_Float16)a.x; v[1] = (_Float16)a.y; v[2] = (_Float16)a.z; v[3] = (_Float16)a.w;
    v[4] = (_Float16)b.x; v[5] = (_Float16)b.y; v[6] = (_Float16)b.z; v[7] = (_Float16)b.w;
    *(f16x8*)&X16[i] = v;
}

// xg chunk GEMM v2: M = 128*Tc, N = 1024, K = 256.
// R9 diagnosis of the stable ~355 us non-rec gap: the (2Tc,16) grid re-read
// every A-row from 16 blocks scattered across XCDs -> 537 MB of redundant A
// traffic at L3 rates (~300 us). v2: grid (2Tc, 1); each block loads its
// A-frags ONCE into registers (33.6 MB total A traffic) and loops n0 over
// all 16 B-tiles. B (512 KB) re-reads stay hot in each XCD's 4 MB L2.
// MFMA phase, epilogue, and xg layout are unchanged from the verified
// kernel — just looped, with two 4-wave barriers per n0 (st reuse).
__global__ __launch_bounds__(256) void xg_gemm_mfma(const __half* __restrict__ X16,
                                                    const __half* __restrict__ Wg16,
                                                    const float* __restrict__ bias_p,
                                                    __half* __restrict__ xg,
                                                    int t0, int lTc, int tcMask) {
    __shared__ __align__(16) __half st[4][16][72];
    int tid = threadIdx.x;
    int w = tid >> 6, lane = tid & 63;
    int row16 = lane & 15, quad = lane >> 4;
    int m0 = blockIdx.x * 64 + w * 16;

    int mrow = m0 + row16;                                   // chunk-local row
    size_t xrow = (size_t)(mrow >> lTc) * 512 + t0 + (mrow & tcMask);
    const __half* aptr = X16 + xrow * 256 + quad * 8;
    f16x8 afrag[8];
#pragma unroll
    for (int kk = 0; kk < 8; ++kk)
        afrag[kk] = *(const f16x8*)(aptr + kk * 32);

    int ml = lane >> 2, cq = lane & 3;
    int mout = blockIdx.x * 64 + w * 16 + ml;                // chunk-local row
    __half* xgo = xg + (size_t)mout * 1024 + cq * 16;

    for (int n0 = 0; n0 < 1024; n0 += 64) {
#pragma unroll
        for (int cg = 0; cg < 4; ++cg) {
            int n = n0 + cg * 16 + row16;
            const __half* bptr = Wg16 + (size_t)n * 256 + quad * 8;
            f32x4 acc = {0.0f, 0.0f, 0.0f, 0.0f};
#pragma unroll
            for (int kk = 0; kk < 8; ++kk) {
                f16x8 bfrag = *(const f16x8*)(bptr + kk * 32);
                acc = __builtin_amdgcn_mfma_f32_16x16x32_f16(afrag[kk], bfrag, acc, 0, 0, 0);
            }
            float bias = bias_p[n];
#pragma unroll
            for (int r = 0; r < 4; ++r)
                st[w][quad * 4 + r][cg * 16 + row16] = __float2half(acc[r] + bias);
        }
        __syncthreads();
        const uint4* src = (const uint4*)&st[w][ml][cq * 16];
        uint4 v0 = src[0], v1 = src[1];
        *(uint4*)&xgo[n0] = v0;
        *(uint4*)&xgo[n0 + 8] = v1;
        __syncthreads();
    }
}

// Recurrence v7 (= R6, measured-best 880 us): wreg[44] unpinned (allocator
// remats ~half into per-step L1 loads — every attempt to force more
// residency regressed: R2 "+v" pin, R3/R8 AGPR reads, R7 over-budget AGPR,
// R9 4-wave TLP), lw 19 k-pairs [i][c][kh] sequential (conflict-free),
// hs[2][272] padded (conflicts -> 0), 1 k-pair streamed.
// Thread (c = tid>>1, kh = tid&1): 4 gates of col c, k-half kh (64 k-pairs).
__global__ __launch_bounds__(512, 2) void lstm_rec4(const __half* __restrict__ xg,
                                                    const __half* __restrict__ Wh16,
                                                    const int* __restrict__ x_len,
                                                    float* __restrict__ out,
                                                    __half* __restrict__ h_state,
                                                    float* __restrict__ c_state,
                                                    int t0, int Tc) {
    __shared__ __align__(16) uint4 lw[9728];        // [i<19][c<256][kh<2] : 152 KB
    __shared__ __align__(16) __half hs[2][272];     // padded double-buffered h
    int tid = threadIdx.x;
    int c = tid >> 1, kh = tid & 1;
    int b = blockIdx.x;
    int len = x_len[b];
    const uint4* W4 = (const uint4*)Wh16;           // index: p*256 + c  (p = k-pair)

    // LDS fill: element j = i*512 + c2*2 + kh2 <- k-pair (kh2*64 + 44 + i), col c2
    for (int j = tid; j < 9728; j += 512) {
        int i2 = j >> 9, c2 = (j >> 1) & 255, kh2 = j & 1;
        lw[j] = W4[(size_t)(kh2 * 64 + 44 + i2) * 256 + c2];
    }
    // Register-resident weights (allocator-managed): k-pairs kh*64 + 0..43
    const uint4* wp = W4 + (size_t)(kh * 64) * 256 + c;
    uint4 wreg[44];
#pragma unroll
    for (int i = 0; i < 44; ++i) wreg[i] = wp[(size_t)i * 256];

    float cst = 0.0f;
    float hlast = 0.0f;
    if (t0 != 0) cst = c_state[b * 256 + c];        // replicated in both lanes
    if (kh == 0)
        hs[0][c + ((c >> 7) << 4)] = (t0 == 0) ? __float2half(0.0f)
                                               : h_state[b * 256 + c];

    const __half* xgb = xg + (size_t)b * Tc * 1024 + 4 * c;
    float* outb = out + ((size_t)b * 512 + t0) * 256 + c;
    const uint4* lwb = lw + tid;                    // [i*512] strides
    __syncthreads();

    for (int tt = 0; tt < Tc; ++tt) {
        // streamed weight + xg first (in flight during resident dot2s)
        uint4 s0 = wp[(size_t)63 * 256];
        uint2 xr = *(const uint2*)(xgb + (size_t)tt * 1024);

        // kh-half base: kh=0 -> uint4 idx 0, kh=1 -> idx 18 (byte 288)
        const uint4* h4 = (const uint4*)(hs[tt & 1]) + kh * 18;
        float4 acc = {0.0f, 0.0f, 0.0f, 0.0f};
        // j = 0..10: k-pairs 0..43 in wreg (allocator: regs or remat loads)
#pragma unroll
        for (int j = 0; j < 11; ++j) {
            uint4 hv = h4[j];
            dot4_(acc, wreg[j * 4 + 0], __builtin_bit_cast(h2_t, hv.x));
            dot4_(acc, wreg[j * 4 + 1], __builtin_bit_cast(h2_t, hv.y));
            dot4_(acc, wreg[j * 4 + 2], __builtin_bit_cast(h2_t, hv.z));
            dot4_(acc, wreg[j * 4 + 3], __builtin_bit_cast(h2_t, hv.w));
        }
        // j = 11..14: k-pairs 44..59 from LDS (i = 0..15)
#pragma unroll
        for (int j = 11; j < 15; ++j) {
            uint4 hv = h4[j];
            int i0 = (j - 11) * 4;
            dot4_(acc, lwb[(i0 + 0) * 512], __builtin_bit_cast(h2_t, hv.x));
            dot4_(acc, lwb[(i0 + 1) * 512], __builtin_bit_cast(h2_t, hv.y));
            dot4_(acc, lwb[(i0 + 2) * 512], __builtin_bit_cast(h2_t, hv.z));
            dot4_(acc, lwb[(i0 + 3) * 512], __builtin_bit_cast(h2_t, hv.w));
        }
        // j = 15: k-pairs 60,61,62 LDS (i = 16,17,18) + 63 streamed
        {
            uint4 hv = h4[15];
            dot4_(acc, lwb[16 * 512], __builtin_bit_cast(h2_t, hv.x));
            dot4_(acc, lwb[17 * 512], __builtin_bit_cast(h2_t, hv.y));
            dot4_(acc, lwb[18 * 512], __builtin_bit_cast(h2_t, hv.z));
            dot4_(acc, s0, __builtin_bit_cast(h2_t, hv.w));
        }
        // reduce partials over kh (lanes l, l^1) on the VALU pipe
        float gi = pair_sum_(acc.x);
        float gf = pair_sum_(acc.y);
        float gg = pair_sum_(acc.z);
        float go = pair_sum_(acc.w);
        h2_t x01 = __builtin_bit_cast(h2_t, xr.x);
        h2_t x23 = __builtin_bit_cast(h2_t, xr.y);
        gi += (float)x01.x;
        gf += (float)x01.y;
        gg += (float)x23.x;
        go += (float)x23.y;
        // gate math: both lanes redundantly (identical inputs -> identical cst)
        float iv = sigmoidf_(gi), fv = sigmoidf_(gf);
        float gv = tanhf_(gg),   ov = sigmoidf_(go);
        cst = fv * cst + iv * gv;
        float h = ov * tanhf_(cst);
        hlast = h;
        if (kh == 0) {
            outb[(size_t)tt * 256] = (t0 + tt < len) ? h : 0.0f;
            hs[(tt & 1) ^ 1][c + ((c >> 7) << 4)] = __float2half(h);
        }
        __syncthreads();
    }
    if (kh == 0) {
        h_state[b * 256 + c] = __float2half(hlast);
        c_state[b * 256 + c] = cst;
    }
}

// Fallback (ws too small for any xg chunk): fused, streams both fp16 matrices.
__global__ __launch_bounds__(1024) void lstm_fused16(const float* __restrict__ X,
                                                     const __half* __restrict__ Wi16,
                                                     const __half* __restrict__ Wh16,
                                                     const float* __restrict__ bias_p,
                                                     const int* __restrict__ x_len,
                                                     float* __restrict__ out) {
    __shared__ __half hs_h[256];
    __shared__ __half xs_h[256];
    __shared__ float4 part[3][256];
    int tid = threadIdx.x;
    int c = tid & 255, kh = tid >> 8;
    int b = blockIdx.x;
    int len = x_len[b];
    float cst = 0.0f;
    float4 bias;
    if (kh == 0) {
        bias = *(const float4*)&bias_p[4 * c];
        hs_h[c] = __float2half(0.0f);
    }
    const uint4* wph = (const uint4*)(Wh16 + (size_t)(kh * 32) * 2048 + 8 * c);
    const uint4* wpi = (const uint4*)(Wi16 + (size_t)(kh * 32) * 2048 + 8 * c);
    float* outb = out + (size_t)b * 512 * 256 + c;
    __syncthreads();

    for (int t = 0; t < TT; ++t) {
        if (tid < 128) {
            float2 xv = *(const float2*)&X[((size_t)b * 512 + t) * 256 + 2 * tid];
            h2_t xh = {(_Float16)xv.x, (_Float16)xv.y};
            ((h2_t*)xs_h)[tid] = xh;
        }
        __syncthreads();
        float4 acc = {0.0f, 0.0f, 0.0f, 0.0f};
#pragma unroll 4
        for (int i = 0; i < 32; ++i) {
            uint4 uh = wph[(size_t)i * 256];
            uint4 ui = wpi[(size_t)i * 256];
            h2_t hv = ((const h2_t*)hs_h)[kh * 32 + i];
            h2_t xv = ((const h2_t*)xs_h)[kh * 32 + i];
            dot4_(acc, uh, hv);
            dot4_(acc, ui, xv);
        }
        if (kh) part[kh - 1][c] = acc;
        __syncthreads();
        if (kh == 0) {
            float4 p0 = part[0][c], p1 = part[1][c], p2 = part[2][c];
            float gi = acc.x + p0.x + p1.x + p2.x + bias.x;
            float gf = acc.y + p0.y + p1.y + p2.y + bias.y;
            float gg = acc.z + p0.z + p1.z + p2.z + bias.z;
            float go = acc.w + p0.w + p1.w + p2.w + bias.w;
            float iv = sigmoidf_(gi), fv = sigmoidf_(gf);
            float gv = tanhf_(gg),   ov = sigmoidf_(go);
            cst = fv * cst + iv * gv;
            float h = ov * tanhf_(cst);
            outb[(size_t)t * 256] = (t < len) ? h : 0.0f;
            hs_h[c] = __float2half(h);
        }
        __syncthreads();
    }
}

extern "C" void kernel_launch(void* const* d_in, const int* in_sizes, int n_in,
                              void* d_out, int out_size, void* d_ws, size_t ws_size,
                              hipStream_t stream) {
    const float* x     = (const float*)d_in[0];
    const int*   x_len = (const int*)d_in[1];
    const float* W_ih  = (const float*)d_in[2];
    const float* W_hh  = (const float*)d_in[3];
    const float* b_ih  = (const float*)d_in[4];
    const float* b_hh  = (const float*)d_in[5];
    float* out = (float*)d_out;

    char* ws = (char*)d_ws;
    __half* Wh16    = (__half*)(ws);                      // 512 KB
    __half* Wi16    = (__half*)(ws + 0x080000);           // 512 KB
    __half* Wg16    = (__half*)(ws + 0x100000);           // 512 KB
    float*  bias_p  = (float*)(ws + 0x180000);            // 4 KB
    __half* h_state = (__half*)(ws + 0x181000);           // 64 KB
    float*  c_state = (float*)(ws + 0x191000);            // 128 KB
    __half* x16     = (__half*)(ws + 0x1B1000);           // 33.6 MB
    size_t  o_xg    = 0x1B1000 + (size_t)0x2004000;
    __half* xg      = (__half*)(ws + o_xg);

    int Tc = 0;
    for (int cand = 512; cand >= 16; cand >>= 1)
        if (ws_size >= o_xg + (size_t)cand * 262144) { Tc = cand; break; }

    pack2<<<1024, 256, 0, stream>>>(W_ih, W_hh, b_ih, b_hh,
                                    Wg16, Wi16, Wh16, bias_p);
    if (Tc) {
        cvt_x<<<8192, 256, 0, stream>>>(x, x16);
        int lTc = 31 - __builtin_clz((unsigned)Tc);
        for (int t0 = 0; t0 < TT; t0 += Tc) {
            xg_gemm_mfma<<<2 * Tc, 256, 0, stream>>>(x16, Wg16, bias_p, xg,
                                                     t0, lTc, Tc - 1);
            lstm_rec4<<<BB, 512, 0, stream>>>(xg, Wh16, x_len, out,
                                              h_state, c_state, t0, Tc);
        }
    } else {
        lstm_fused16<<<BB, 1024, 0, stream>>>(x, Wi16, Wh16, bias_p, x_len, out);
    }
}

// Round 11
// 1104.989 us; speedup vs baseline: 3.7733x; 1.0801x over previous
//
#include <hip/hip_runtime.h>
#include <hip/hip_fp16.h>
#include <math.h>

#define BB 128
#define TT 512
#define DD 256
#define HH 256
#define NG 1024  // 4*H

typedef _Float16 h2_t __attribute__((ext_vector_type(2)));
typedef _Float16 f16x8 __attribute__((ext_vector_type(8)));
typedef float f32x4 __attribute__((ext_vector_type(4)));

#if __has_builtin(__builtin_amdgcn_fdot2)
__device__ __forceinline__ float fdot2_(h2_t a, h2_t b, float c) {
    return __builtin_amdgcn_fdot2(a, b, c, false);
}
#else
__device__ __forceinline__ float fdot2_(h2_t a, h2_t b, float c) {
    return c + (float)a.x * (float)b.x + (float)a.y * (float)b.y;
}
#endif

__device__ __forceinline__ float sigmoidf_(float x) {
    return 1.0f / (1.0f + __expf(-x));
}
__device__ __forceinline__ float tanhf_(float x) {
    x = fminf(15.0f, fmaxf(-15.0f, x));
    float e = __expf(2.0f * x);
    return (e - 1.0f) / (e + 1.0f);
}
__device__ __forceinline__ void dot4_(float4& acc, uint4 u, h2_t h) {
    acc.x = fdot2_(__builtin_bit_cast(h2_t, u.x), h, acc.x);
    acc.y = fdot2_(__builtin_bit_cast(h2_t, u.y), h, acc.y);
    acc.z = fdot2_(__builtin_bit_cast(h2_t, u.z), h, acc.z);
    acc.w = fdot2_(__builtin_bit_cast(h2_t, u.w), h, acc.w);
}

// Pair sum across lanes (l, l^1) via DPP quad_perm [1,0,3,2] — VALU pipe,
// no LDS traffic.
#if __has_builtin(__builtin_amdgcn_update_dpp)
__device__ __forceinline__ float pair_sum_(float v) {
    int x = __builtin_bit_cast(int, v);
    int y = __builtin_amdgcn_update_dpp(0, x, 0xB1, 0xF, 0xF, true);
    return v + __builtin_bit_cast(float, y);
}
#else
__device__ __forceinline__ float pair_sum_(float v) {
    return v + __shfl_xor(v, 1, 64);
}
#endif

// Pack: packed col n = j*4+q <-> gate row g = q*256+j  (q: 0=i,1=f,2=g,3=o)
//  Wg16 [n][k] fp16            (MFMA GEMM B operand)
//  Wi16/Wh16 fp16 k-pair-major (halfs at ((k>>1)*1024 + n)*2 + (k&1))
//  bias_p[n] = b_ih[g] + b_hh[g]
__global__ void pack2(const float* __restrict__ W_ih, const float* __restrict__ W_hh,
                      const float* __restrict__ b_ih, const float* __restrict__ b_hh,
                      __half* __restrict__ Wg16, __half* __restrict__ Wi16,
                      __half* __restrict__ Wh16, float* __restrict__ bias_p) {
    int idx = blockIdx.x * 256 + threadIdx.x;   // 0..262143
    int n = idx >> 8;
    int k = idx & 255;
    int g = (n & 3) * 256 + (n >> 2);
    float wih = W_ih[g * 256 + k];
    float whh = W_hh[g * 256 + k];
    Wg16[n * 256 + k] = __float2half(wih);
    size_t hidx = ((size_t)(k >> 1) * 1024 + n) * 2 + (k & 1);
    Wi16[hidx] = __float2half(wih);
    Wh16[hidx] = __float2half(whh);
    if (idx < 1024) {
        int gg = (idx & 3) * 256 + (idx >> 2);
        bias_p[idx] = b_ih[gg] + b_hh[gg];
    }
}

// xg chunk GEMM v3: M = 128*Tc, N = 1024, K = 256. Grid (2Tc).
// R10 audit of the residual ~309 us non-rec gap: (1) all 4 waves of a block
// read the SAME B-tile from global -> 2 GB through the 64 B/cyc L1 port;
// (2) un-prefetched load->MFMA serialization per n0; (3) cvt_x's separate
// 100 MB pass. v3: B-tile (32 KB) staged in LDS once per block (4x reuse at
// LDS rate), register-prefetched one tile ahead (T14: issue early, ds_write
// after the epilogue barrier); additive-rotate swizzle u' = (u+r)&31 on the
// uint4 index makes both ds_write (same r, distinct u) and the MFMA
// ds_read_b128 (bank group (quad+r)%8, 8 lanes per 4-bank group = exact
// minimum) conflict-free. f32->f16 A conversion fused into the A-frag load
// (cvt_x kernel and x16 buffer deleted).
__global__ __launch_bounds__(256) void xg_gemm_mfma(const float* __restrict__ X,
                                                    const __half* __restrict__ Wg16,
                                                    const float* __restrict__ bias_p,
                                                    __half* __restrict__ xg,
                                                    int t0, int lTc, int tcMask) {
    __shared__ __align__(16) uint4 bs[2048];          // B tile, swizzled: 32 KB
    __shared__ __align__(16) __half st[4][16][72];    // epilogue transpose: 9 KB
    int tid = threadIdx.x;
    int w = tid >> 6, lane = tid & 63;
    int row16 = lane & 15, quad = lane >> 4;
    int m0 = blockIdx.x * 64 + w * 16;

    int mrow = m0 + row16;                                   // chunk-local row
    size_t xrow = (size_t)(mrow >> lTc) * 512 + t0 + (mrow & tcMask);
    const float* aptr = X + xrow * 256 + quad * 8;
    f16x8 afrag[8];
#pragma unroll
    for (int kk = 0; kk < 8; ++kk) {
        float4 a = *(const float4*)(aptr + kk * 32);
        float4 b = *(const float4*)(aptr + kk * 32 + 4);
        f16x8 v;
        v[0] = (_Float16)a.x; v[1] = (_Float16)a.y; v[2] = (_Float16)a.z; v[3] = (_Float16)a.w;
        v[4] = (_Float16)b.x; v[5] = (_Float16)b.y; v[6] = (_Float16)b.z; v[7] = (_Float16)b.w;
        afrag[kk] = v;
    }

    const uint4* Bg = (const uint4*)Wg16;   // row n = 32 uint4
    uint4 breg[8];
    // prologue: tile n0 = 0 -> LDS
#pragma unroll
    for (int i = 0; i < 8; ++i) {
        int idx = tid + i * 256;
        int r = idx >> 5, u = idx & 31;
        breg[i] = Bg[(size_t)r * 32 + u];
    }
#pragma unroll
    for (int i = 0; i < 8; ++i) {
        int idx = tid + i * 256;
        int r = idx >> 5, u = idx & 31;
        bs[r * 32 + ((u + r) & 31)] = breg[i];
    }
    __syncthreads();

    int ml = lane >> 2, cq = lane & 3;
    int mout = blockIdx.x * 64 + w * 16 + ml;                // chunk-local row
    __half* xgo = xg + (size_t)mout * 1024 + cq * 16;

    for (int n0 = 0; n0 < 1024; n0 += 64) {
        // prefetch next B tile into registers (consumed after the barrier)
        if (n0 + 64 < 1024) {
#pragma unroll
            for (int i = 0; i < 8; ++i) {
                int idx = tid + i * 256;
                int r = idx >> 5, u = idx & 31;
                breg[i] = Bg[(size_t)(n0 + 64 + r) * 32 + u];
            }
        }
#pragma unroll
        for (int cg = 0; cg < 4; ++cg) {
            int r = cg * 16 + row16;
            f32x4 acc = {0.0f, 0.0f, 0.0f, 0.0f};
#pragma unroll
            for (int kk = 0; kk < 8; ++kk) {
                int u = quad + 4 * kk;
                f16x8 bfrag = __builtin_bit_cast(f16x8, bs[r * 32 + ((u + r) & 31)]);
                acc = __builtin_amdgcn_mfma_f32_16x16x32_f16(afrag[kk], bfrag, acc, 0, 0, 0);
            }
            float bias = bias_p[n0 + cg * 16 + row16];
#pragma unroll
            for (int q = 0; q < 4; ++q)
                st[w][quad * 4 + q][cg * 16 + row16] = __float2half(acc[q] + bias);
        }
        __syncthreads();           // st ready; all bs reads of this tile done
        const uint4* src = (const uint4*)&st[w][ml][cq * 16];
        uint4 v0 = src[0], v1 = src[1];
        *(uint4*)&xgo[n0] = v0;
        *(uint4*)&xgo[n0 + 8] = v1;
        if (n0 + 64 < 1024) {
#pragma unroll
            for (int i = 0; i < 8; ++i) {
                int idx = tid + i * 256;
                int r = idx >> 5, u = idx & 31;
                bs[r * 32 + ((u + r) & 31)] = breg[i];
            }
        }
        __syncthreads();           // bs holds next tile; st readable done
    }
}

// Recurrence v7 (= R6/R10, measured-best 880-884 us): wreg[44] unpinned
// (allocator remats ~half into per-step L1 loads — every attempt to force
// more residency regressed: R2 "+v" pin, R3/R8 AGPR reads, R7 over-budget
// AGPR, R9 4-wave TLP), lw 19 k-pairs [i][c][kh] sequential (conflict-free),
// hs[2][272] padded (conflicts -> 0), 1 k-pair streamed.
// Thread (c = tid>>1, kh = tid&1): 4 gates of col c, k-half kh (64 k-pairs).
__global__ __launch_bounds__(512, 2) void lstm_rec4(const __half* __restrict__ xg,
                                                    const __half* __restrict__ Wh16,
                                                    const int* __restrict__ x_len,
                                                    float* __restrict__ out,
                                                    __half* __restrict__ h_state,
                                                    float* __restrict__ c_state,
                                                    int t0, int Tc) {
    __shared__ __align__(16) uint4 lw[9728];        // [i<19][c<256][kh<2] : 152 KB
    __shared__ __align__(16) __half hs[2][272];     // padded double-buffered h
    int tid = threadIdx.x;
    int c = tid >> 1, kh = tid & 1;
    int b = blockIdx.x;
    int len = x_len[b];
    const uint4* W4 = (const uint4*)Wh16;           // index: p*256 + c  (p = k-pair)

    // LDS fill: element j = i*512 + c2*2 + kh2 <- k-pair (kh2*64 + 44 + i), col c2
    for (int j = tid; j < 9728; j += 512) {
        int i2 = j >> 9, c2 = (j >> 1) & 255, kh2 = j & 1;
        lw[j] = W4[(size_t)(kh2 * 64 + 44 + i2) * 256 + c2];
    }
    // Register-resident weights (allocator-managed): k-pairs kh*64 + 0..43
    const uint4* wp = W4 + (size_t)(kh * 64) * 256 + c;
    uint4 wreg[44];
#pragma unroll
    for (int i = 0; i < 44; ++i) wreg[i] = wp[(size_t)i * 256];

    float cst = 0.0f;
    float hlast = 0.0f;
    if (t0 != 0) cst = c_state[b * 256 + c];        // replicated in both lanes
    if (kh == 0)
        hs[0][c + ((c >> 7) << 4)] = (t0 == 0) ? __float2half(0.0f)
                                               : h_state[b * 256 + c];

    const __half* xgb = xg + (size_t)b * Tc * 1024 + 4 * c;
    float* outb = out + ((size_t)b * 512 + t0) * 256 + c;
    const uint4* lwb = lw + tid;                    // [i*512] strides
    __syncthreads();

    for (int tt = 0; tt < Tc; ++tt) {
        // streamed weight + xg first (in flight during resident dot2s)
        uint4 s0 = wp[(size_t)63 * 256];
        uint2 xr = *(const uint2*)(xgb + (size_t)tt * 1024);

        // kh-half base: kh=0 -> uint4 idx 0, kh=1 -> idx 18 (byte 288)
        const uint4* h4 = (const uint4*)(hs[tt & 1]) + kh * 18;
        float4 acc = {0.0f, 0.0f, 0.0f, 0.0f};
        // j = 0..10: k-pairs 0..43 in wreg (allocator: regs or remat loads)
#pragma unroll
        for (int j = 0; j < 11; ++j) {
            uint4 hv = h4[j];
            dot4_(acc, wreg[j * 4 + 0], __builtin_bit_cast(h2_t, hv.x));
            dot4_(acc, wreg[j * 4 + 1], __builtin_bit_cast(h2_t, hv.y));
            dot4_(acc, wreg[j * 4 + 2], __builtin_bit_cast(h2_t, hv.z));
            dot4_(acc, wreg[j * 4 + 3], __builtin_bit_cast(h2_t, hv.w));
        }
        // j = 11..14: k-pairs 44..59 from LDS (i = 0..15)
#pragma unroll
        for (int j = 11; j < 15; ++j) {
            uint4 hv = h4[j];
            int i0 = (j - 11) * 4;
            dot4_(acc, lwb[(i0 + 0) * 512], __builtin_bit_cast(h2_t, hv.x));
            dot4_(acc, lwb[(i0 + 1) * 512], __builtin_bit_cast(h2_t, hv.y));
            dot4_(acc, lwb[(i0 + 2) * 512], __builtin_bit_cast(h2_t, hv.z));
            dot4_(acc, lwb[(i0 + 3) * 512], __builtin_bit_cast(h2_t, hv.w));
        }
        // j = 15: k-pairs 60,61,62 LDS (i = 16,17,18) + 63 streamed
        {
            uint4 hv = h4[15];
            dot4_(acc, lwb[16 * 512], __builtin_bit_cast(h2_t, hv.x));
            dot4_(acc, lwb[17 * 512], __builtin_bit_cast(h2_t, hv.y));
            dot4_(acc, lwb[18 * 512], __builtin_bit_cast(h2_t, hv.z));
            dot4_(acc, s0, __builtin_bit_cast(h2_t, hv.w));
        }
        // reduce partials over kh (lanes l, l^1) on the VALU pipe
        float gi = pair_sum_(acc.x);
        float gf = pair_sum_(acc.y);
        float gg = pair_sum_(acc.z);
        float go = pair_sum_(acc.w);
        h2_t x01 = __builtin_bit_cast(h2_t, xr.x);
        h2_t x23 = __builtin_bit_cast(h2_t, xr.y);
        gi += (float)x01.x;
        gf += (float)x01.y;
        gg += (float)x23.x;
        go += (float)x23.y;
        // gate math: both lanes redundantly (identical inputs -> identical cst)
        float iv = sigmoidf_(gi), fv = sigmoidf_(gf);
        float gv = tanhf_(gg),   ov = sigmoidf_(go);
        cst = fv * cst + iv * gv;
        float h = ov * tanhf_(cst);
        hlast = h;
        if (kh == 0) {
            outb[(size_t)tt * 256] = (t0 + tt < len) ? h : 0.0f;
            hs[(tt & 1) ^ 1][c + ((c >> 7) << 4)] = __float2half(h);
        }
        __syncthreads();
    }
    if (kh == 0) {
        h_state[b * 256 + c] = __float2half(hlast);
        c_state[b * 256 + c] = cst;
    }
}

// Fallback (ws too small for any xg chunk): fused, streams both fp16 matrices.
__global__ __launch_bounds__(1024) void lstm_fused16(const float* __restrict__ X,
                                                     const __half* __restrict__ Wi16,
                                                     const __half* __restrict__ Wh16,
                                                     const float* __restrict__ bias_p,
                                                     const int* __restrict__ x_len,
                                                     float* __restrict__ out) {
    __shared__ __half hs_h[256];
    __shared__ __half xs_h[256];
    __shared__ float4 part[3][256];
    int tid = threadIdx.x;
    int c = tid & 255, kh = tid >> 8;
    int b = blockIdx.x;
    int len = x_len[b];
    float cst = 0.0f;
    float4 bias;
    if (kh == 0) {
        bias = *(const float4*)&bias_p[4 * c];
        hs_h[c] = __float2half(0.0f);
    }
    const uint4* wph = (const uint4*)(Wh16 + (size_t)(kh * 32) * 2048 + 8 * c);
    const uint4* wpi = (const uint4*)(Wi16 + (size_t)(kh * 32) * 2048 + 8 * c);
    float* outb = out + (size_t)b * 512 * 256 + c;
    __syncthreads();

    for (int t = 0; t < TT; ++t) {
        if (tid < 128) {
            float2 xv = *(const float2*)&X[((size_t)b * 512 + t) * 256 + 2 * tid];
            h2_t xh = {(_Float16)xv.x, (_Float16)xv.y};
            ((h2_t*)xs_h)[tid] = xh;
        }
        __syncthreads();
        float4 acc = {0.0f, 0.0f, 0.0f, 0.0f};
#pragma unroll 4
        for (int i = 0; i < 32; ++i) {
            uint4 uh = wph[(size_t)i * 256];
            uint4 ui = wpi[(size_t)i * 256];
            h2_t hv = ((const h2_t*)hs_h)[kh * 32 + i];
            h2_t xv = ((const h2_t*)xs_h)[kh * 32 + i];
            dot4_(acc, uh, hv);
            dot4_(acc, ui, xv);
        }
        if (kh) part[kh - 1][c] = acc;
        __syncthreads();
        if (kh == 0) {
            float4 p0 = part[0][c], p1 = part[1][c], p2 = part[2][c];
            float gi = acc.x + p0.x + p1.x + p2.x + bias.x;
            float gf = acc.y + p0.y + p1.y + p2.y + bias.y;
            float gg = acc.z + p0.z + p1.z + p2.z + bias.z;
            float go = acc.w + p0.w + p1.w + p2.w + bias.w;
            float iv = sigmoidf_(gi), fv = sigmoidf_(gf);
            float gv = tanhf_(gg),   ov = sigmoidf_(go);
            cst = fv * cst + iv * gv;
            float h = ov * tanhf_(cst);
            outb[(size_t)t * 256] = (t < len) ? h : 0.0f;
            hs_h[c] = __float2half(h);
        }
        __syncthreads();
    }
}

extern "C" void kernel_launch(void* const* d_in, const int* in_sizes, int n_in,
                              void* d_out, int out_size, void* d_ws, size_t ws_size,
                              hipStream_t stream) {
    const float* x     = (const float*)d_in[0];
    const int*   x_len = (const int*)d_in[1];
    const float* W_ih  = (const float*)d_in[2];
    const float* W_hh  = (const float*)d_in[3];
    const float* b_ih  = (const float*)d_in[4];
    const float* b_hh  = (const float*)d_in[5];
    float* out = (float*)d_out;

    char* ws = (char*)d_ws;
    __half* Wh16    = (__half*)(ws);                      // 512 KB
    __half* Wi16    = (__half*)(ws + 0x080000);           // 512 KB
    __half* Wg16    = (__half*)(ws + 0x100000);           // 512 KB
    float*  bias_p  = (float*)(ws + 0x180000);            // 4 KB
    __half* h_state = (__half*)(ws + 0x181000);           // 64 KB
    float*  c_state = (float*)(ws + 0x191000);            // 128 KB
    __half* xg      = (__half*)(ws + 0x1B1000);           // Tc*256 KB

    int Tc = 0;
    for (int cand = 512; cand >= 16; cand >>= 1)
        if (ws_size >= 0x1B1000 + (size_t)cand * 262144) { Tc = cand; break; }

    pack2<<<1024, 256, 0, stream>>>(W_ih, W_hh, b_ih, b_hh,
                                    Wg16, Wi16, Wh16, bias_p);
    if (Tc) {
        int lTc = 31 - __builtin_clz((unsigned)Tc);
        for (int t0 = 0; t0 < TT; t0 += Tc) {
            xg_gemm_mfma<<<2 * Tc, 256, 0, stream>>>(x, Wg16, bias_p, xg,
                                                     t0, lTc, Tc - 1);
            lstm_rec4<<<BB, 512, 0, stream>>>(xg, Wh16, x_len, out,
                                              h_state, c_state, t0, Tc);
        }
    } else {
        lstm_fused16<<<BB, 1024, 0, stream>>>(x, Wi16, Wh16, bias_p, x_len, out);
    }
}

// Round 12
// 1042.316 us; speedup vs baseline: 4.0002x; 1.0601x over previous
//
#include <hip/hip_runtime.h>
#include <hip/hip_fp16.h>
#include <math.h>

#define BB 128
#define TT 512
#define DD 256
#define HH 256
#define NG 1024  // 4*H

typedef _Float16 h2_t __attribute__((ext_vector_type(2)));
typedef _Float16 f16x8 __attribute__((ext_vector_type(8)));
typedef float f32x4 __attribute__((ext_vector_type(4)));

#if __has_builtin(__builtin_amdgcn_fdot2)
__device__ __forceinline__ float fdot2_(h2_t a, h2_t b, float c) {
    return __builtin_amdgcn_fdot2(a, b, c, false);
}
#else
__device__ __forceinline__ float fdot2_(h2_t a, h2_t b, float c) {
    return c + (float)a.x * (float)b.x + (float)a.y * (float)b.y;
}
#endif

__device__ __forceinline__ float sigmoidf_(float x) {
    return 1.0f / (1.0f + __expf(-x));
}
__device__ __forceinline__ float tanhf_(float x) {
    x = fminf(15.0f, fmaxf(-15.0f, x));
    float e = __expf(2.0f * x);
    return (e - 1.0f) / (e + 1.0f);
}
__device__ __forceinline__ void dot4_(float4& acc, uint4 u, h2_t h) {
    acc.x = fdot2_(__builtin_bit_cast(h2_t, u.x), h, acc.x);
    acc.y = fdot2_(__builtin_bit_cast(h2_t, u.y), h, acc.y);
    acc.z = fdot2_(__builtin_bit_cast(h2_t, u.z), h, acc.z);
    acc.w = fdot2_(__builtin_bit_cast(h2_t, u.w), h, acc.w);
}

// Pair sum across lanes (l, l^1) via DPP quad_perm [1,0,3,2] — VALU pipe,
// no LDS traffic.
#if __has_builtin(__builtin_amdgcn_update_dpp)
__device__ __forceinline__ float pair_sum_(float v) {
    int x = __builtin_bit_cast(int, v);
    int y = __builtin_amdgcn_update_dpp(0, x, 0xB1, 0xF, 0xF, true);
    return v + __builtin_bit_cast(float, y);
}
#else
__device__ __forceinline__ float pair_sum_(float v) {
    return v + __shfl_xor(v, 1, 64);
}
#endif

// Pack: packed col n = j*4+q <-> gate row g = q*256+j  (q: 0=i,1=f,2=g,3=o)
//  Wg16 [n][k] fp16            (MFMA GEMM B operand)
//  Wi16/Wh16 fp16 k-pair-major (halfs at ((k>>1)*1024 + n)*2 + (k&1))
//  bias_p[n] = b_ih[g] + b_hh[g]
__global__ void pack2(const float* __restrict__ W_ih, const float* __restrict__ W_hh,
                      const float* __restrict__ b_ih, const float* __restrict__ b_hh,
                      __half* __restrict__ Wg16, __half* __restrict__ Wi16,
                      __half* __restrict__ Wh16, float* __restrict__ bias_p) {
    int idx = blockIdx.x * 256 + threadIdx.x;   // 0..262143
    int n = idx >> 8;
    int k = idx & 255;
    int g = (n & 3) * 256 + (n >> 2);
    float wih = W_ih[g * 256 + k];
    float whh = W_hh[g * 256 + k];
    Wg16[n * 256 + k] = __float2half(wih);
    size_t hidx = ((size_t)(k >> 1) * 1024 + n) * 2 + (k & 1);
    Wi16[hidx] = __float2half(wih);
    Wh16[hidx] = __float2half(whh);
    if (idx < 1024) {
        int gg = (idx & 3) * 256 + (idx >> 2);
        bias_p[idx] = b_ih[gg] + b_hh[gg];
    }
}

// xg chunk GEMM v4: M = 128*Tc, N = 1024, K = 256. Grid (Tc), 128 rows/block.
// R11 audit: v3's ~180 us is ~4x its roofline (A 134 MB + xg 134 MB HBM ~43
// us; 34 GFLOP ~17 us). Causes: single 8-deep dependent MFMA chain per cg
// (dep-latency-stalled), no cross-block overlap headroom. v4:
//  - 128 A-rows/block (2 m-tiles/wave): per cg TWO independent acc chains
//    interleave -> dep stalls halved per MFMA; B staging traffic halved.
//  - LDS 50 KB (bs 32 + st 18) -> 3 blocks/CU co-resident; barriers of one
//    block overlap compute of another.
//  - Same proven bs swizzle u' = (u+r)&31, same breg prefetch schedule,
//    same epilogue transpose (2 sub-tiles/wave), fused f32->f16 A load.
__global__ __launch_bounds__(256) void xg_gemm_mfma(const float* __restrict__ X,
                                                    const __half* __restrict__ Wg16,
                                                    const float* __restrict__ bias_p,
                                                    __half* __restrict__ xg,
                                                    int t0, int lTc, int tcMask) {
    __shared__ __align__(16) uint4 bs[2048];          // B tile, swizzled: 32 KB
    __shared__ __align__(16) __half st[4][32][72];    // epilogue transpose: 18 KB
    int tid = threadIdx.x;
    int w = tid >> 6, lane = tid & 63;
    int row16 = lane & 15, quad = lane >> 4;
    int m0 = blockIdx.x * 128 + w * 32;

    // A fragments: 2 m-tiles x 8 k-slices, f32 -> f16 fused
    f16x8 afrag[2][8];
#pragma unroll
    for (int mt = 0; mt < 2; ++mt) {
        int mrow = m0 + mt * 16 + row16;                     // chunk-local row
        size_t xrow = (size_t)(mrow >> lTc) * 512 + t0 + (mrow & tcMask);
        const float* aptr = X + xrow * 256 + quad * 8;
#pragma unroll
        for (int kk = 0; kk < 8; ++kk) {
            float4 a = *(const float4*)(aptr + kk * 32);
            float4 b = *(const float4*)(aptr + kk * 32 + 4);
            f16x8 v;
            v[0] = (_Float16)a.x; v[1] = (_Float16)a.y; v[2] = (_Float16)a.z; v[3] = (_Float16)a.w;
            v[4] = (_Float16)b.x; v[5] = (_Float16)b.y; v[6] = (_Float16)b.z; v[7] = (_Float16)b.w;
            afrag[mt][kk] = v;
        }
    }

    const uint4* Bg = (const uint4*)Wg16;   // row n = 32 uint4
    uint4 breg[8];
    // prologue: tile n0 = 0 -> LDS
#pragma unroll
    for (int i = 0; i < 8; ++i) {
        int idx = tid + i * 256;
        int r = idx >> 5, u = idx & 31;
        breg[i] = Bg[(size_t)r * 32 + u];
    }
#pragma unroll
    for (int i = 0; i < 8; ++i) {
        int idx = tid + i * 256;
        int r = idx >> 5, u = idx & 31;
        bs[r * 32 + ((u + r) & 31)] = breg[i];
    }
    __syncthreads();

    int ml = lane >> 2, cq = lane & 3;

    for (int n0 = 0; n0 < 1024; n0 += 64) {
        // prefetch next B tile into registers (consumed after the barrier)
        if (n0 + 64 < 1024) {
#pragma unroll
            for (int i = 0; i < 8; ++i) {
                int idx = tid + i * 256;
                int r = idx >> 5, u = idx & 31;
                breg[i] = Bg[(size_t)(n0 + 64 + r) * 32 + u];
            }
        }
#pragma unroll
        for (int cg = 0; cg < 4; ++cg) {
            int r = cg * 16 + row16;
            f32x4 acc0 = {0.0f, 0.0f, 0.0f, 0.0f};
            f32x4 acc1 = {0.0f, 0.0f, 0.0f, 0.0f};
#pragma unroll
            for (int kk = 0; kk < 8; ++kk) {
                int u = quad + 4 * kk;
                f16x8 bfrag = __builtin_bit_cast(f16x8, bs[r * 32 + ((u + r) & 31)]);
                acc0 = __builtin_amdgcn_mfma_f32_16x16x32_f16(afrag[0][kk], bfrag, acc0, 0, 0, 0);
                acc1 = __builtin_amdgcn_mfma_f32_16x16x32_f16(afrag[1][kk], bfrag, acc1, 0, 0, 0);
            }
            float bias = bias_p[n0 + cg * 16 + row16];
#pragma unroll
            for (int q = 0; q < 4; ++q) {
                st[w][quad * 4 + q][cg * 16 + row16] = __float2half(acc0[q] + bias);
                st[w][16 + quad * 4 + q][cg * 16 + row16] = __float2half(acc1[q] + bias);
            }
        }
        __syncthreads();           // st ready; all bs reads of this tile done
#pragma unroll
        for (int h = 0; h < 2; ++h) {
            int mout = blockIdx.x * 128 + w * 32 + h * 16 + ml;  // chunk-local
            const uint4* src = (const uint4*)&st[w][h * 16 + ml][cq * 16];
            uint4 v0 = src[0], v1 = src[1];
            __half* xgo = xg + (size_t)mout * 1024 + n0 + cq * 16;
            *(uint4*)&xgo[0] = v0;
            *(uint4*)&xgo[8] = v1;
        }
        if (n0 + 64 < 1024) {
#pragma unroll
            for (int i = 0; i < 8; ++i) {
                int idx = tid + i * 256;
                int r = idx >> 5, u = idx & 31;
                bs[r * 32 + ((u + r) & 31)] = breg[i];
            }
        }
        __syncthreads();           // bs holds next tile; st reads done
    }
}

// Recurrence v7 (= R6/R10/R11, measured-best 877-886 us): wreg[44] unpinned
// (allocator remats ~half into per-step L1 loads — every attempt to force
// more residency regressed: R2 "+v" pin, R3/R8 AGPR reads, R7 over-budget
// AGPR, R9 4-wave TLP), lw 19 k-pairs [i][c][kh] sequential (conflict-free),
// hs[2][272] padded (conflicts -> 0), 1 k-pair streamed.
// Thread (c = tid>>1, kh = tid&1): 4 gates of col c, k-half kh (64 k-pairs).
__global__ __launch_bounds__(512, 2) void lstm_rec4(const __half* __restrict__ xg,
                                                    const __half* __restrict__ Wh16,
                                                    const int* __restrict__ x_len,
                                                    float* __restrict__ out,
                                                    __half* __restrict__ h_state,
                                                    float* __restrict__ c_state,
                                                    int t0, int Tc) {
    __shared__ __align__(16) uint4 lw[9728];        // [i<19][c<256][kh<2] : 152 KB
    __shared__ __align__(16) __half hs[2][272];     // padded double-buffered h
    int tid = threadIdx.x;
    int c = tid >> 1, kh = tid & 1;
    int b = blockIdx.x;
    int len = x_len[b];
    const uint4* W4 = (const uint4*)Wh16;           // index: p*256 + c  (p = k-pair)

    // LDS fill: element j = i*512 + c2*2 + kh2 <- k-pair (kh2*64 + 44 + i), col c2
    for (int j = tid; j < 9728; j += 512) {
        int i2 = j >> 9, c2 = (j >> 1) & 255, kh2 = j & 1;
        lw[j] = W4[(size_t)(kh2 * 64 + 44 + i2) * 256 + c2];
    }
    // Register-resident weights (allocator-managed): k-pairs kh*64 + 0..43
    const uint4* wp = W4 + (size_t)(kh * 64) * 256 + c;
    uint4 wreg[44];
#pragma unroll
    for (int i = 0; i < 44; ++i) wreg[i] = wp[(size_t)i * 256];

    float cst = 0.0f;
    float hlast = 0.0f;
    if (t0 != 0) cst = c_state[b * 256 + c];        // replicated in both lanes
    if (kh == 0)
        hs[0][c + ((c >> 7) << 4)] = (t0 == 0) ? __float2half(0.0f)
                                               : h_state[b * 256 + c];

    const __half* xgb = xg + (size_t)b * Tc * 1024 + 4 * c;
    float* outb = out + ((size_t)b * 512 + t0) * 256 + c;
    const uint4* lwb = lw + tid;                    // [i*512] strides
    __syncthreads();

    for (int tt = 0; tt < Tc; ++tt) {
        // streamed weight + xg first (in flight during resident dot2s)
        uint4 s0 = wp[(size_t)63 * 256];
        uint2 xr = *(const uint2*)(xgb + (size_t)tt * 1024);

        // kh-half base: kh=0 -> uint4 idx 0, kh=1 -> idx 18 (byte 288)
        const uint4* h4 = (const uint4*)(hs[tt & 1]) + kh * 18;
        float4 acc = {0.0f, 0.0f, 0.0f, 0.0f};
        // j = 0..10: k-pairs 0..43 in wreg (allocator: regs or remat loads)
#pragma unroll
        for (int j = 0; j < 11; ++j) {
            uint4 hv = h4[j];
            dot4_(acc, wreg[j * 4 + 0], __builtin_bit_cast(h2_t, hv.x));
            dot4_(acc, wreg[j * 4 + 1], __builtin_bit_cast(h2_t, hv.y));
            dot4_(acc, wreg[j * 4 + 2], __builtin_bit_cast(h2_t, hv.z));
            dot4_(acc, wreg[j * 4 + 3], __builtin_bit_cast(h2_t, hv.w));
        }
        // j = 11..14: k-pairs 44..59 from LDS (i = 0..15)
#pragma unroll
        for (int j = 11; j < 15; ++j) {
            uint4 hv = h4[j];
            int i0 = (j - 11) * 4;
            dot4_(acc, lwb[(i0 + 0) * 512], __builtin_bit_cast(h2_t, hv.x));
            dot4_(acc, lwb[(i0 + 1) * 512], __builtin_bit_cast(h2_t, hv.y));
            dot4_(acc, lwb[(i0 + 2) * 512], __builtin_bit_cast(h2_t, hv.z));
            dot4_(acc, lwb[(i0 + 3) * 512], __builtin_bit_cast(h2_t, hv.w));
        }
        // j = 15: k-pairs 60,61,62 LDS (i = 16,17,18) + 63 streamed
        {
            uint4 hv = h4[15];
            dot4_(acc, lwb[16 * 512], __builtin_bit_cast(h2_t, hv.x));
            dot4_(acc, lwb[17 * 512], __builtin_bit_cast(h2_t, hv.y));
            dot4_(acc, lwb[18 * 512], __builtin_bit_cast(h2_t, hv.z));
            dot4_(acc, s0, __builtin_bit_cast(h2_t, hv.w));
        }
        // reduce partials over kh (lanes l, l^1) on the VALU pipe
        float gi = pair_sum_(acc.x);
        float gf = pair_sum_(acc.y);
        float gg = pair_sum_(acc.z);
        float go = pair_sum_(acc.w);
        h2_t x01 = __builtin_bit_cast(h2_t, xr.x);
        h2_t x23 = __builtin_bit_cast(h2_t, xr.y);
        gi += (float)x01.x;
        gf += (float)x01.y;
        gg += (float)x23.x;
        go += (float)x23.y;
        // gate math: both lanes redundantly (identical inputs -> identical cst)
        float iv = sigmoidf_(gi), fv = sigmoidf_(gf);
        float gv = tanhf_(gg),   ov = sigmoidf_(go);
        cst = fv * cst + iv * gv;
        float h = ov * tanhf_(cst);
        hlast = h;
        if (kh == 0) {
            outb[(size_t)tt * 256] = (t0 + tt < len) ? h : 0.0f;
            hs[(tt & 1) ^ 1][c + ((c >> 7) << 4)] = __float2half(h);
        }
        __syncthreads();
    }
    if (kh == 0) {
        h_state[b * 256 + c] = __float2half(hlast);
        c_state[b * 256 + c] = cst;
    }
}

// Fallback (ws too small for any xg chunk): fused, streams both fp16 matrices.
__global__ __launch_bounds__(1024) void lstm_fused16(const float* __restrict__ X,
                                                     const __half* __restrict__ Wi16,
                                                     const __half* __restrict__ Wh16,
                                                     const float* __restrict__ bias_p,
                                                     const int* __restrict__ x_len,
                                                     float* __restrict__ out) {
    __shared__ __half hs_h[256];
    __shared__ __half xs_h[256];
    __shared__ float4 part[3][256];
    int tid = threadIdx.x;
    int c = tid & 255, kh = tid >> 8;
    int b = blockIdx.x;
    int len = x_len[b];
    float cst = 0.0f;
    float4 bias;
    if (kh == 0) {
        bias = *(const float4*)&bias_p[4 * c];
        hs_h[c] = __float2half(0.0f);
    }
    const uint4* wph = (const uint4*)(Wh16 + (size_t)(kh * 32) * 2048 + 8 * c);
    const uint4* wpi = (const uint4*)(Wi16 + (size_t)(kh * 32) * 2048 + 8 * c);
    float* outb = out + (size_t)b * 512 * 256 + c;
    __syncthreads();

    for (int t = 0; t < TT; ++t) {
        if (tid < 128) {
            float2 xv = *(const float2*)&X[((size_t)b * 512 + t) * 256 + 2 * tid];
            h2_t xh = {(_Float16)xv.x, (_Float16)xv.y};
            ((h2_t*)xs_h)[tid] = xh;
        }
        __syncthreads();
        float4 acc = {0.0f, 0.0f, 0.0f, 0.0f};
#pragma unroll 4
        for (int i = 0; i < 32; ++i) {
            uint4 uh = wph[(size_t)i * 256];
            uint4 ui = wpi[(size_t)i * 256];
            h2_t hv = ((const h2_t*)hs_h)[kh * 32 + i];
            h2_t xv = ((const h2_t*)xs_h)[kh * 32 + i];
            dot4_(acc, uh, hv);
            dot4_(acc, ui, xv);
        }
        if (kh) part[kh - 1][c] = acc;
        __syncthreads();
        if (kh == 0) {
            float4 p0 = part[0][c], p1 = part[1][c], p2 = part[2][c];
            float gi = acc.x + p0.x + p1.x + p2.x + bias.x;
            float gf = acc.y + p0.y + p1.y + p2.y + bias.y;
            float gg = acc.z + p0.z + p1.z + p2.z + bias.z;
            float go = acc.w + p0.w + p1.w + p2.w + bias.w;
            float iv = sigmoidf_(gi), fv = sigmoidf_(gf);
            float gv = tanhf_(gg),   ov = sigmoidf_(go);
            cst = fv * cst + iv * gv;
            float h = ov * tanhf_(cst);
            outb[(size_t)t * 256] = (t < len) ? h : 0.0f;
            hs_h[c] = __float2half(h);
        }
        __syncthreads();
    }
}

extern "C" void kernel_launch(void* const* d_in, const int* in_sizes, int n_in,
                              void* d_out, int out_size, void* d_ws, size_t ws_size,
                              hipStream_t stream) {
    const float* x     = (const float*)d_in[0];
    const int*   x_len = (const int*)d_in[1];
    const float* W_ih  = (const float*)d_in[2];
    const float* W_hh  = (const float*)d_in[3];
    const float* b_ih  = (const float*)d_in[4];
    const float* b_hh  = (const float*)d_in[5];
    float* out = (float*)d_out;

    char* ws = (char*)d_ws;
    __half* Wh16    = (__half*)(ws);                      // 512 KB
    __half* Wi16    = (__half*)(ws + 0x080000);           // 512 KB
    __half* Wg16    = (__half*)(ws + 0x100000);           // 512 KB
    float*  bias_p  = (float*)(ws + 0x180000);            // 4 KB
    __half* h_state = (__half*)(ws + 0x181000);           // 64 KB
    float*  c_state = (float*)(ws + 0x191000);            // 128 KB
    __half* xg      = (__half*)(ws + 0x1B1000);           // Tc*256 KB

    int Tc = 0;
    for (int cand = 512; cand >= 16; cand >>= 1)
        if (ws_size >= 0x1B1000 + (size_t)cand * 262144) { Tc = cand; break; }

    pack2<<<1024, 256, 0, stream>>>(W_ih, W_hh, b_ih, b_hh,
                                    Wg16, Wi16, Wh16, bias_p);
    if (Tc) {
        int lTc = 31 - __builtin_clz((unsigned)Tc);
        for (int t0 = 0; t0 < TT; t0 += Tc) {
            xg_gemm_mfma<<<Tc, 256, 0, stream>>>(x, Wg16, bias_p, xg,
                                                 t0, lTc, Tc - 1);
            lstm_rec4<<<BB, 512, 0, stream>>>(xg, Wh16, x_len, out,
                                              h_state, c_state, t0, Tc);
        }
    } else {
        lstm_fused16<<<BB, 1024, 0, stream>>>(x, Wi16, Wh16, bias_p, x_len, out);
    }
}